// Round 18
// baseline (524.751 us; speedup 1.0000x reference)
//
#include <hip/hip_runtime.h>

constexpr int B = 8, N = 8192, S = 2048, D = 64, K = 16, C = 3 + D;
constexpr int G = 4;        // queries per wave
constexpr int GD = 16;      // grid cells per axis
constexpr int CELLS = GD * GD * GD;

// Map float -> monotonically sortable unsigned (total order matches float <)
__device__ __forceinline__ unsigned sortable(float f) {
    unsigned u = __float_as_uint(f);
    unsigned mask = (unsigned)(((int)u) >> 31) | 0x80000000u;
    return u ^ mask;
}

__device__ __forceinline__ float uload(const float* p) {
    return __uint_as_float(__builtin_amdgcn_readfirstlane(__float_as_uint(*p)));
}

// Scalar reference-exact distance (fallback path): dot asc-FMA, d=(pn-2dot)+qn [R8]
__device__ __forceinline__ float make_d(float px, float py, float pz, float pnv,
                                        float qx, float qy, float qz, float qn) {
    float dot = __fmaf_rn(pz, qz, __fmaf_rn(py, qy, __fmul_rn(px, qx)));
    return __fadd_rn(__fsub_rn(pnv, __fmul_rn(2.0f, dot)), qn);
}

// EXACT v = pn - dot2; dot2 = fma(pz,q2z, fma(py,q2y, px*q2x)) == 2*dot bitwise
__device__ __forceinline__ float make_v(float px, float py, float pz, float pnv,
                                        float q2x, float q2y, float q2z) {
    float dot2 = __fmaf_rn(pz, q2z, __fmaf_rn(py, q2y, __fmul_rn(px, q2x)));
    return __fsub_rn(pnv, dot2);
}

__device__ __forceinline__ int cell_of(float x) {
    int c = (int)floorf(__fmul_rn(__fadd_rn(x, 4.0f), 2.0f));
    return c < 0 ? 0 : (c > GD - 1 ? GD - 1 : c);
}

__device__ __forceinline__ unsigned long long bitonic_sort64_u64(unsigned long long v, int lane) {
#pragma unroll
    for (int k = 2; k <= 64; k <<= 1)
#pragma unroll
        for (int j = k >> 1; j > 0; j >>= 1) {
            unsigned long long o = __shfl_xor(v, j, 64);
            bool keepmin = ((lane & k) == 0) == ((lane & j) == 0);
            v = ((v < o) == keepmin) ? v : o;
        }
    return v;
}

__global__ void zero_kernel(int* counts) {
    int t = blockIdx.x * blockDim.x + threadIdx.x;
    if (t < B * CELLS) counts[t] = 0;
}

// pts4[b][n] = {x,y,z,||p||^2} (desc no-FMA norm, verified R8) + fused histogram
__global__ void pack_kernel(const float* __restrict__ pts, float4* __restrict__ pts4,
                            int* __restrict__ counts) {
    int t = blockIdx.x * blockDim.x + threadIdx.x;
    if (t >= B * N) return;
    int b = t >> 13, n = t & (N - 1);
    const float* P = pts + (size_t)b * 3 * N;
    float x = P[n], y = P[N + n], z = P[2 * N + n];
    float pn = __fadd_rn(__fadd_rn(__fmul_rn(z, z), __fmul_rn(y, y)), __fmul_rn(x, x));
    pts4[t] = make_float4(x, y, z, pn);
    int cid = (cell_of(z) * GD + cell_of(y)) * GD + cell_of(x);
    atomicAdd(&counts[b * CELLS + cid], 1);
}

// Per-batch exclusive prefix over 4096 cell counts; writes starts (+sentinel) and cursor.
__global__ void __launch_bounds__(1024) prefix_kernel(const int* __restrict__ counts,
                                                      int* __restrict__ starts,
                                                      int* __restrict__ cursor) {
    __shared__ int sdata[1024];
    int b = blockIdx.x, t = threadIdx.x;
    const int* cb = counts + b * CELLS;
    int c0 = t * 4;
    int l0 = cb[c0], l1 = cb[c0 + 1], l2 = cb[c0 + 2], l3 = cb[c0 + 3];
    int mysum = l0 + l1 + l2 + l3;
    sdata[t] = mysum;
    __syncthreads();
    for (int off = 1; off < 1024; off <<= 1) {
        int v = (t >= off) ? sdata[t - off] : 0;
        __syncthreads();
        sdata[t] += v;
        __syncthreads();
    }
    int excl = sdata[t] - mysum;
    int* sb = starts + b * (CELLS + 1);
    int* ub = cursor + b * CELLS;
    sb[c0] = excl;                 ub[c0] = excl;
    sb[c0 + 1] = excl + l0;        ub[c0 + 1] = excl + l0;
    sb[c0 + 2] = excl + l0 + l1;   ub[c0 + 2] = excl + l0 + l1;
    sb[c0 + 3] = excl + l0 + l1 + l2; ub[c0 + 3] = excl + l0 + l1 + l2;
    if (t == 1023) sb[CELLS] = N;
}

// Counting-sort scatter: binned[b] = pts4[b] grouped by cell.
__global__ void scatter_kernel(const float4* __restrict__ pts4, int* __restrict__ cursor,
                               float4* __restrict__ binned) {
    int t = blockIdx.x * blockDim.x + threadIdx.x;
    if (t >= B * N) return;
    int b = t >> 13;
    float4 c = pts4[t];
    int cid = (cell_of(c.z) * GD + cell_of(c.y)) * GD + cell_of(c.x);
    int pos = atomicAdd(&cursor[b * CELLS + cid], 1);
    binned[(size_t)b * N + pos] = c;
}

// One lane per query: expanding Chebyshev shells; keep 16 smallest EXACT d over
// >=16 distinct scanned points; tau = 16th-smallest => provably >= global d16.
// Binning quality only affects tau tightness, never correctness.
__global__ void __launch_bounds__(256) tau_kernel(const float4* __restrict__ binned,
                                                  const int* __restrict__ starts,
                                                  const float* __restrict__ newp,
                                                  float* __restrict__ tau) {
    int t = blockIdx.x * blockDim.x + threadIdx.x;  // b*S + s
    if (t >= B * S) return;
    int b = t >> 11, s = t & (S - 1);
    const float* Q = newp + (size_t)b * 3 * S;
    float qx = Q[s], qy = Q[S + s], qz = Q[2 * S + s];
    float qn = __fadd_rn(__fadd_rn(__fmul_rn(qz, qz), __fmul_rn(qy, qy)), __fmul_rn(qx, qx));
    float q2x = 2.0f * qx, q2y = 2.0f * qy, q2z = 2.0f * qz;
    int cx = cell_of(qx), cy = cell_of(qy), cz = cell_of(qz);
    const float4* P = binned + (size_t)b * N;
    const int* st = starts + b * (CELLS + 1);
    float dbest[16];
#pragma unroll
    for (int i = 0; i < 16; ++i) dbest[i] = __int_as_float(0x7f800000);
    int collected = 0;
    for (int r = 0; r < GD; ++r) {
        int zlo = cz - r < 0 ? 0 : cz - r, zhi = cz + r > GD - 1 ? GD - 1 : cz + r;
        int ylo = cy - r < 0 ? 0 : cy - r, yhi = cy + r > GD - 1 ? GD - 1 : cy + r;
        int xlo = cx - r < 0 ? 0 : cx - r, xhi = cx + r > GD - 1 ? GD - 1 : cx + r;
        for (int z = zlo; z <= zhi; ++z)
            for (int y = ylo; y <= yhi; ++y)
                for (int x = xlo; x <= xhi; ++x) {
                    int adx = x - cx < 0 ? cx - x : x - cx;
                    int ady = y - cy < 0 ? cy - y : y - cy;
                    int adz = z - cz < 0 ? cz - z : z - cz;
                    int ad = adx > ady ? adx : ady;
                    ad = ad > adz ? ad : adz;
                    if (ad != r) continue;  // shell only (no duplicates)
                    int cid = (z * GD + y) * GD + x;
                    int p0 = st[cid], p1 = st[cid + 1];
                    for (int p = p0; p < p1; ++p) {
                        float4 c = P[p];
                        float v = make_v(c.x, c.y, c.z, c.w, q2x, q2y, q2z);
                        float d = __fadd_rn(v, qn);  // same ops as knn pass-2
                        if (d < dbest[15]) {
#pragma unroll
                            for (int i = 15; i >= 1; --i) {
                                float lo = dbest[i - 1];
                                dbest[i] = d < lo ? lo : (d < dbest[i] ? d : dbest[i]);
                            }
                            dbest[0] = d < dbest[0] ? d : dbest[0];
                        }
                        ++collected;
                    }
                }
        if (collected >= 16) break;
    }
    tau[t] = dbest[15];
}

// feat [B][D][N] -> featT [B][N][D], LDS-tiled 64x64
__global__ void __launch_bounds__(256) transpose_kernel(const float* __restrict__ feat,
                                                        float* __restrict__ featT) {
    __shared__ float tile[64][65];
    int b = blockIdx.x >> 7;
    int n0 = (blockIdx.x & 127) << 6;
    int col = threadIdx.x & 63;
    int crow = threadIdx.x >> 6;
    const float* F = feat + (size_t)b * D * N;
#pragma unroll
    for (int i = 0; i < 16; ++i) {
        int c = i * 4 + crow;
        tile[c][col] = F[(size_t)c * N + n0 + col];
    }
    __syncthreads();
    float* FT = featT + ((size_t)b * N + n0) * D;
#pragma unroll
    for (int i = 0; i < 16; ++i) {
        int nl = i * 4 + crow;
        FT[(size_t)nl * D + col] = tile[col][nl];
    }
}

// knn: single scan with precomputed tau. Prefilter v <= vthr (superset), hits
// recompute exact d, LDS-atomic compact into 128 slots, exact u64 sort (+merge
// path for 65..128). cnt<16 or >128 -> exact full fallback (never expected).
__global__ void __launch_bounds__(256) knn_kernel(const float4* __restrict__ pts4,
                                                  const float* __restrict__ newp,
                                                  const float* __restrict__ tau,
                                                  int* __restrict__ ind) {
    __shared__ unsigned long long buf[4][G][128];
    __shared__ int cnt_lds[4][G];
    int wib = threadIdx.x >> 6;
    int lane = threadIdx.x & 63;
    int wid = blockIdx.x * 4 + wib;
    int b = wid >> 9;
    int sbase = (wid & 511) * G;
    const float4* P4 = pts4 + (size_t)b * N;
    const float* Q = newp + (size_t)b * 3 * S;
    if (lane < G) cnt_lds[wib][lane] = 0;
    float qn[G], q2x[G], q2y[G], q2z[G], tau_d[G], vthr[G];
#pragma unroll
    for (int g = 0; g < G; ++g) {
        int s = sbase + g;
        float qx = uload(Q + s), qy = uload(Q + S + s), qz = uload(Q + 2 * S + s);
        qn[g] = __fadd_rn(__fadd_rn(__fmul_rn(qz, qz), __fmul_rn(qy, qy)), __fmul_rn(qx, qx));
        q2x[g] = 2.0f * qx;
        q2y[g] = 2.0f * qy;
        q2z[g] = 2.0f * qz;
        tau_d[g] = uload(tau + (b << 11) + s);  // exact-witness bound >= d16
        vthr[g] = __fadd_rn(__fsub_rn(tau_d[g], qn[g]), 1e-4f);  // superset prefilter
    }

    // ---- single scan: prefilter on v, exact check + LDS-atomic compact ----
    for (int blk = 0; blk < N / 256; ++blk) {
        int nb = blk * 256 + lane;
        float4 c0 = P4[nb], c1 = P4[nb + 64], c2 = P4[nb + 128], c3 = P4[nb + 192];
#pragma unroll
        for (int g = 0; g < G; ++g) {
            float vv[4];
            vv[0] = make_v(c0.x, c0.y, c0.z, c0.w, q2x[g], q2y[g], q2z[g]);
            vv[1] = make_v(c1.x, c1.y, c1.z, c1.w, q2x[g], q2y[g], q2z[g]);
            vv[2] = make_v(c2.x, c2.y, c2.z, c2.w, q2x[g], q2y[g], q2z[g]);
            vv[3] = make_v(c3.x, c3.y, c3.z, c3.w, q2x[g], q2y[g], q2z[g]);
#pragma unroll
            for (int i = 0; i < 4; ++i) {
                if (vv[i] <= vthr[g]) {  // rare divergent branch
                    float d = __fadd_rn(vv[i], qn[g]);  // exact reference d
                    if (d <= tau_d[g]) {
                        int pos = atomicAdd(&cnt_lds[wib][g], 1);
                        if (pos < 128)
                            buf[wib][g][pos] =
                                ((unsigned long long)sortable(d) << 32) | (unsigned)(nb + i * 64);
                    }
                }
            }
        }
    }
    __syncthreads();

#pragma unroll
    for (int g = 0; g < G; ++g) {
        int cnt = cnt_lds[wib][g];
        int* my_ind = ind + ((size_t)b * S + sbase + g) * K;
        if (cnt >= K && cnt <= 128) {
            int lim = cnt < 64 ? cnt : 64;
            unsigned long long a = (lane < lim) ? buf[wib][g][lane] : ~0ull;
            a = bitonic_sort64_u64(a, lane);
            unsigned long long c = a;
            if (cnt > 64) {
                unsigned long long bk = (64 + lane < cnt) ? buf[wib][g][64 + lane] : ~0ull;
                bk = bitonic_sort64_u64(bk, lane);
                unsigned long long brev = __shfl(bk, 63 - lane, 64);
                c = a < brev ? a : brev;  // lower half of 64+64 merge (bitonic)
#pragma unroll
                for (int j = 32; j > 0; j >>= 1) {
                    unsigned long long o = __shfl_xor(c, j, 64);
                    bool keepmin = (lane & j) == 0;
                    c = ((c < o) == keepmin) ? c : o;
                }
            }
            if (lane < K) my_ind[lane] = (int)(unsigned)c;
        } else {
            // Exact fallback (never expected): full per-wave rescan.
            float qx = 0.5f * q2x[g], qy = 0.5f * q2y[g], qz = 0.5f * q2z[g];
            unsigned long long a[K];
#pragma unroll
            for (int i = 0; i < K; ++i) a[i] = ~0ull;
            for (int n = lane; n < N; n += 64) {
                float4 c = P4[n];
                float d = make_d(c.x, c.y, c.z, c.w, qx, qy, qz, qn[g]);
                unsigned long long key = ((unsigned long long)sortable(d) << 32) | (unsigned)n;
                if (key < a[K - 1]) {
#pragma unroll
                    for (int i = K - 1; i >= 1; --i) {
                        unsigned long long lo = a[i - 1];
                        a[i] = key < lo ? lo : (key < a[i] ? key : a[i]);
                    }
                    a[0] = key < a[0] ? key : a[0];
                }
            }
            for (int r = 0; r < K; ++r) {
                unsigned long long best = a[0];
#pragma unroll
                for (int mm = 1; mm < 64; mm <<= 1) {
                    unsigned long long o = __shfl_xor(best, mm, 64);
                    best = o < best ? o : best;
                }
                if (lane == 0) my_ind[r] = (int)(unsigned)best;
                bool won = (a[0] == best);
#pragma unroll
                for (int i = 0; i < K - 1; ++i) a[i] = won ? a[i + 1] : a[i];
                a[K - 1] = won ? ~0ull : a[K - 1];
            }
        }
    }
}

// ===== gather: LDS-staged tile (verified R17) =====
__global__ void __launch_bounds__(256) gather_tile_kernel(const float4* __restrict__ pts4,
                                                          const float* __restrict__ newp,
                                                          const float* __restrict__ featT,
                                                          const int* __restrict__ ind,
                                                          float* __restrict__ out) {
    __shared__ float tile[64][69];
    int bid = blockIdx.x;
    int b = bid >> 9;
    int k = (bid >> 5) & (K - 1);
    int s0 = (bid & 31) << 6;
    int j = threadIdx.x >> 2;
    int p = threadIdx.x & 3;
    int s = s0 + j;
    int id = ind[((size_t)b * S + s) * K + k];
    const float* row = featT + ((size_t)b * N + id) * D;
#pragma unroll
    for (int i = 0; i < 4; ++i) {
        int f = p + 4 * i;
        float4 v = *(const float4*)(row + f * 4);
        *(float4*)(&tile[j][3 + f * 4]) = v;
    }
    if (p == 0) {
        float4 pt = pts4[(size_t)b * N + id];
        const float* Q = newp + (size_t)b * 3 * S;
        tile[j][0] = __fsub_rn(pt.x, Q[s]);
        tile[j][1] = __fsub_rn(pt.y, Q[S + s]);
        tile[j][2] = __fsub_rn(pt.z, Q[2 * S + s]);
    }
    __syncthreads();
    size_t KS = (size_t)K * S;
    float* ob = out + ((size_t)b * C * K + k) * S + s0;
#pragma unroll
    for (int it = 0; it < 17; ++it) {
        int c = it * 4 + (threadIdx.x >> 6);
        int l = threadIdx.x & 63;
        if (c < C) ob[(size_t)c * KS + l] = tile[l][c];
    }
}

// Fallback gather (no featT workspace)
__global__ void __launch_bounds__(256) gather_kernel(const float4* __restrict__ pts4,
                                                     const float* __restrict__ newp,
                                                     const float* __restrict__ feat,
                                                     const int* __restrict__ ind,
                                                     float* __restrict__ out) {
    int t = blockIdx.x * blockDim.x + threadIdx.x;
    int s = t & (S - 1);
    int k = (t >> 11) & (K - 1);
    int rest = t >> 15;
    int g = rest % 17;
    int b = rest / 17;
    if (b >= B) return;
    int id = ind[((size_t)b * S + s) * K + k];
    size_t KS = (size_t)K * S;
    if (g == 0) {
        float4 p = pts4[(size_t)b * N + id];
        const float* Q = newp + (size_t)b * 3 * S;
        float* o = out + ((size_t)b * C * K + k) * S + s;
        o[0] = __fsub_rn(p.x, Q[s]);
        o[KS] = __fsub_rn(p.y, Q[S + s]);
        o[2 * KS] = __fsub_rn(p.z, Q[2 * S + s]);
    } else {
        int cb = (g - 1) * 4;
        const float* F = feat + (size_t)b * D * N;
        float4 f = make_float4(F[(size_t)cb * N + id], F[(size_t)(cb + 1) * N + id],
                               F[(size_t)(cb + 2) * N + id], F[(size_t)(cb + 3) * N + id]);
        float* o = out + (((size_t)b * C + 3 + cb) * K + k) * S + s;
        o[0] = f.x;
        o[KS] = f.y;
        o[2 * KS] = f.z;
        o[3 * KS] = f.w;
    }
}

extern "C" void kernel_launch(void* const* d_in, const int* in_sizes, int n_in,
                              void* d_out, int out_size, void* d_ws, size_t ws_size,
                              hipStream_t stream) {
    const float* pts = (const float*)d_in[0];   // [B, 3, N]
    const float* newp = (const float*)d_in[1];  // [B, 3, S]
    const float* feat = (const float*)d_in[2];  // [B, D, N]
    float* out = (float*)d_out;                 // [B, C, K, S]

    size_t off = 0;
    int* ind = (int*)((char*)d_ws + off);           off += (size_t)B * S * K * sizeof(int);
    float4* pts4 = (float4*)((char*)d_ws + off);    off += (size_t)B * N * sizeof(float4);
    float4* binned = (float4*)((char*)d_ws + off);  off += (size_t)B * N * sizeof(float4);
    int* counts = (int*)((char*)d_ws + off);        off += (size_t)B * CELLS * sizeof(int);
    int* cursor = (int*)((char*)d_ws + off);        off += (size_t)B * CELLS * sizeof(int);
    int* starts = (int*)((char*)d_ws + off);        off += (size_t)B * (CELLS + 1) * sizeof(int);
    float* tau = (float*)((char*)d_ws + off);       off += (size_t)B * S * sizeof(float);
    float* featT = (float*)((char*)d_ws + off);
    size_t need = off + (size_t)B * N * D * sizeof(float);
    int useT = (ws_size >= need) ? 1 : 0;

    zero_kernel<<<(B * CELLS + 255) / 256, 256, 0, stream>>>(counts);
    pack_kernel<<<(B * N) / 256, 256, 0, stream>>>(pts, pts4, counts);
    prefix_kernel<<<B, 1024, 0, stream>>>(counts, starts, cursor);
    scatter_kernel<<<(B * N) / 256, 256, 0, stream>>>(pts4, cursor, binned);
    tau_kernel<<<(B * S) / 256, 256, 0, stream>>>(binned, starts, newp, tau);
    if (useT) transpose_kernel<<<B * (N / 64), 256, 0, stream>>>(feat, featT);
    knn_kernel<<<(B * S) / (G * 4), 256, 0, stream>>>(pts4, newp, tau, ind);
    if (useT)
        gather_tile_kernel<<<B * K * (S / 64), 256, 0, stream>>>(pts4, newp, featT, ind, out);
    else
        gather_kernel<<<(B * 17 * K * S) / 256, 256, 0, stream>>>(pts4, newp, feat, ind, out);
}

// Round 19
// 294.180 us; speedup vs baseline: 1.7838x; 1.7838x over previous
//
#include <hip/hip_runtime.h>

constexpr int B = 8, N = 8192, S = 2048, D = 64, K = 16, C = 3 + D;
constexpr int G = 4;        // queries per wave (knn)
constexpr int GD = 16;      // grid cells per axis
constexpr int CELLS = GD * GD * GD;

__device__ __forceinline__ unsigned sortable(float f) {
    unsigned u = __float_as_uint(f);
    unsigned mask = (unsigned)(((int)u) >> 31) | 0x80000000u;
    return u ^ mask;
}

__device__ __forceinline__ float uload(const float* p) {
    return __uint_as_float(__builtin_amdgcn_readfirstlane(__float_as_uint(*p)));
}

// Scalar reference-exact distance (fallback path): dot asc-FMA, d=(pn-2dot)+qn [R8]
__device__ __forceinline__ float make_d(float px, float py, float pz, float pnv,
                                        float qx, float qy, float qz, float qn) {
    float dot = __fmaf_rn(pz, qz, __fmaf_rn(py, qy, __fmul_rn(px, qx)));
    return __fadd_rn(__fsub_rn(pnv, __fmul_rn(2.0f, dot)), qn);
}

// EXACT v = pn - dot2; dot2 == 2*dot bitwise (pow-2 scale commutes with rounding)
__device__ __forceinline__ float make_v(float px, float py, float pz, float pnv,
                                        float q2x, float q2y, float q2z) {
    float dot2 = __fmaf_rn(pz, q2z, __fmaf_rn(py, q2y, __fmul_rn(px, q2x)));
    return __fsub_rn(pnv, dot2);
}

__device__ __forceinline__ int cell_of(float x) {
    int c = (int)floorf(__fmul_rn(__fadd_rn(x, 4.0f), 2.0f));
    return c < 0 ? 0 : (c > GD - 1 ? GD - 1 : c);
}

__device__ __forceinline__ float bitonic_sort64_f32(float v, int lane) {
#pragma unroll
    for (int k = 2; k <= 64; k <<= 1)
#pragma unroll
        for (int j = k >> 1; j > 0; j >>= 1) {
            float o = __shfl_xor(v, j, 64);
            bool keepmin = ((lane & k) == 0) == ((lane & j) == 0);
            float mn = fminf(v, o), mx = fmaxf(v, o);
            v = keepmin ? mn : mx;
        }
    return v;
}

__device__ __forceinline__ unsigned long long bitonic_sort64_u64(unsigned long long v, int lane) {
#pragma unroll
    for (int k = 2; k <= 64; k <<= 1)
#pragma unroll
        for (int j = k >> 1; j > 0; j >>= 1) {
            unsigned long long o = __shfl_xor(v, j, 64);
            bool keepmin = ((lane & k) == 0) == ((lane & j) == 0);
            v = ((v < o) == keepmin) ? v : o;
        }
    return v;
}

__global__ void zero_kernel(int* counts) {
    int t = blockIdx.x * blockDim.x + threadIdx.x;
    if (t < B * CELLS) counts[t] = 0;
}

// pts4[b][n] = {x,y,z,||p||^2} (desc no-FMA norm, verified R8) + fused histogram
__global__ void pack_kernel(const float* __restrict__ pts, float4* __restrict__ pts4,
                            int* __restrict__ counts) {
    int t = blockIdx.x * blockDim.x + threadIdx.x;
    if (t >= B * N) return;
    int b = t >> 13, n = t & (N - 1);
    const float* P = pts + (size_t)b * 3 * N;
    float x = P[n], y = P[N + n], z = P[2 * N + n];
    float pn = __fadd_rn(__fadd_rn(__fmul_rn(z, z), __fmul_rn(y, y)), __fmul_rn(x, x));
    pts4[t] = make_float4(x, y, z, pn);
    int cid = (cell_of(z) * GD + cell_of(y)) * GD + cell_of(x);
    atomicAdd(&counts[b * CELLS + cid], 1);
}

// Per-batch exclusive prefix over 4096 cell counts; writes starts (+sentinel) and cursor.
__global__ void __launch_bounds__(1024) prefix_kernel(const int* __restrict__ counts,
                                                      int* __restrict__ starts,
                                                      int* __restrict__ cursor) {
    __shared__ int sdata[1024];
    int b = blockIdx.x, t = threadIdx.x;
    const int* cb = counts + b * CELLS;
    int c0 = t * 4;
    int l0 = cb[c0], l1 = cb[c0 + 1], l2 = cb[c0 + 2], l3 = cb[c0 + 3];
    int mysum = l0 + l1 + l2 + l3;
    sdata[t] = mysum;
    __syncthreads();
    for (int off = 1; off < 1024; off <<= 1) {
        int v = (t >= off) ? sdata[t - off] : 0;
        __syncthreads();
        sdata[t] += v;
        __syncthreads();
    }
    int excl = sdata[t] - mysum;
    int* sb = starts + b * (CELLS + 1);
    int* ub = cursor + b * CELLS;
    sb[c0] = excl;                 ub[c0] = excl;
    sb[c0 + 1] = excl + l0;        ub[c0 + 1] = excl + l0;
    sb[c0 + 2] = excl + l0 + l1;   ub[c0 + 2] = excl + l0 + l1;
    sb[c0 + 3] = excl + l0 + l1 + l2; ub[c0 + 3] = excl + l0 + l1 + l2;
    if (t == 1023) sb[CELLS] = N;
}

// Counting-sort scatter: binned[b] = pts4[b] grouped by cell.
__global__ void scatter_kernel(const float4* __restrict__ pts4, int* __restrict__ cursor,
                               float4* __restrict__ binned) {
    int t = blockIdx.x * blockDim.x + threadIdx.x;
    if (t >= B * N) return;
    int b = t >> 13;
    float4 c = pts4[t];
    int cid = (cell_of(c.z) * GD + cell_of(c.y)) * GD + cell_of(c.x);
    int pos = atomicAdd(&cursor[b * CELLS + cid], 1);
    binned[(size_t)b * N + pos] = c;
}

// One WAVE per query: expanding Chebyshev shells, wave-cooperative point loads,
// deterministic LDS compaction (no atomics), stop when cnt>=16 after a shell.
// tau = 16th-smallest exact d of the collected (>=16, <=128) witness set
// => provably >= global d16 (subset 16th >= superset 16th).
__global__ void __launch_bounds__(256) tau_kernel(const float4* __restrict__ binned,
                                                  const int* __restrict__ starts,
                                                  const float* __restrict__ newp,
                                                  float* __restrict__ tau) {
    __shared__ float dbuf[4][128];
    int wib = threadIdx.x >> 6;
    int lane = threadIdx.x & 63;
    int qid = blockIdx.x * 4 + wib;  // b*S + s
    int b = qid >> 11, s = qid & (S - 1);
    const float* Q = newp + (size_t)b * 3 * S;
    float qx = uload(Q + s), qy = uload(Q + S + s), qz = uload(Q + 2 * S + s);
    float qn = __fadd_rn(__fadd_rn(__fmul_rn(qz, qz), __fmul_rn(qy, qy)), __fmul_rn(qx, qx));
    float q2x = 2.0f * qx, q2y = 2.0f * qy, q2z = 2.0f * qz;
    int cx = cell_of(qx), cy = cell_of(qy), cz = cell_of(qz);
    const float4* P = binned + (size_t)b * N;
    const int* st = starts + b * (CELLS + 1);
    int cnt = 0;  // wave-uniform
    for (int r = 0; r < GD && cnt < 16; ++r) {
        int zlo = cz - r < 0 ? 0 : cz - r, zhi = cz + r > GD - 1 ? GD - 1 : cz + r;
        int ylo = cy - r < 0 ? 0 : cy - r, yhi = cy + r > GD - 1 ? GD - 1 : cy + r;
        int xlo = cx - r < 0 ? 0 : cx - r, xhi = cx + r > GD - 1 ? GD - 1 : cx + r;
        for (int z = zlo; z <= zhi; ++z)
            for (int y = ylo; y <= yhi; ++y)
                for (int x = xlo; x <= xhi; ++x) {
                    int adx = x - cx < 0 ? cx - x : x - cx;
                    int ady = y - cy < 0 ? cy - y : y - cy;
                    int adz = z - cz < 0 ? cz - z : z - cz;
                    int ad = adx > ady ? adx : ady;
                    ad = ad > adz ? ad : adz;
                    if (ad != r) continue;  // shell only
                    int cid = (z * GD + y) * GD + x;
                    int p0 = __builtin_amdgcn_readfirstlane(st[cid]);
                    int p1 = __builtin_amdgcn_readfirstlane(st[cid + 1]);
                    int m = p1 - p0;
                    for (int base = 0; base < m; base += 64) {
                        int idx = base + lane;
                        if (idx < m && cnt + idx < 128) {
                            float4 c = P[p0 + idx];
                            float v = make_v(c.x, c.y, c.z, c.w, q2x, q2y, q2z);
                            dbuf[wib][cnt + idx] = __fadd_rn(v, qn);  // exact scheme d
                        }
                    }
                    cnt += m;
                    if (cnt >= 128) { cnt = 128; goto collected; }
                }
    }
collected:
    if (cnt > 128) cnt = 128;
    float a = (lane < cnt) ? dbuf[wib][lane] : __int_as_float(0x7f800000);
    a = bitonic_sort64_f32(a, lane);
    float tv;
    if (cnt > 64) {
        float bk = (64 + lane < cnt) ? dbuf[wib][64 + lane] : __int_as_float(0x7f800000);
        bk = bitonic_sort64_f32(bk, lane);
        float brev = __shfl(bk, 63 - lane, 64);
        float cmin = fminf(a, brev);  // lower half of 64+64 bitonic merge
#pragma unroll
        for (int j = 32; j > 0; j >>= 1) {
            float o = __shfl_xor(cmin, j, 64);
            bool keepmin = (lane & j) == 0;
            float mn = fminf(cmin, o), mx = fmaxf(cmin, o);
            cmin = keepmin ? mn : mx;
        }
        tv = __shfl(cmin, 15, 64);
    } else {
        tv = __shfl(a, 15, 64);
    }
    if (lane == 0) tau[qid] = tv;
}

// feat [B][D][N] -> featT [B][N][D], LDS-tiled 64x64
__global__ void __launch_bounds__(256) transpose_kernel(const float* __restrict__ feat,
                                                        float* __restrict__ featT) {
    __shared__ float tile[64][65];
    int b = blockIdx.x >> 7;
    int n0 = (blockIdx.x & 127) << 6;
    int col = threadIdx.x & 63;
    int crow = threadIdx.x >> 6;
    const float* F = feat + (size_t)b * D * N;
#pragma unroll
    for (int i = 0; i < 16; ++i) {
        int c = i * 4 + crow;
        tile[c][col] = F[(size_t)c * N + n0 + col];
    }
    __syncthreads();
    float* FT = featT + ((size_t)b * N + n0) * D;
#pragma unroll
    for (int i = 0; i < 16; ++i) {
        int nl = i * 4 + crow;
        FT[(size_t)nl * D + col] = tile[col][nl];
    }
}

// knn: single scan with precomputed tau (R18-verified logic).
__global__ void __launch_bounds__(256) knn_kernel(const float4* __restrict__ pts4,
                                                  const float* __restrict__ newp,
                                                  const float* __restrict__ tau,
                                                  int* __restrict__ ind) {
    __shared__ unsigned long long buf[4][G][128];
    __shared__ int cnt_lds[4][G];
    int wib = threadIdx.x >> 6;
    int lane = threadIdx.x & 63;
    int wid = blockIdx.x * 4 + wib;
    int b = wid >> 9;
    int sbase = (wid & 511) * G;
    const float4* P4 = pts4 + (size_t)b * N;
    const float* Q = newp + (size_t)b * 3 * S;
    if (lane < G) cnt_lds[wib][lane] = 0;
    float qn[G], q2x[G], q2y[G], q2z[G], tau_d[G], vthr[G];
#pragma unroll
    for (int g = 0; g < G; ++g) {
        int s = sbase + g;
        float qx = uload(Q + s), qy = uload(Q + S + s), qz = uload(Q + 2 * S + s);
        qn[g] = __fadd_rn(__fadd_rn(__fmul_rn(qz, qz), __fmul_rn(qy, qy)), __fmul_rn(qx, qx));
        q2x[g] = 2.0f * qx;
        q2y[g] = 2.0f * qy;
        q2z[g] = 2.0f * qz;
        tau_d[g] = uload(tau + (b << 11) + s);  // exact-witness bound >= d16
        vthr[g] = __fadd_rn(__fsub_rn(tau_d[g], qn[g]), 1e-4f);  // superset prefilter
    }

    for (int blk = 0; blk < N / 256; ++blk) {
        int nb = blk * 256 + lane;
        float4 c0 = P4[nb], c1 = P4[nb + 64], c2 = P4[nb + 128], c3 = P4[nb + 192];
#pragma unroll
        for (int g = 0; g < G; ++g) {
            float vv[4];
            vv[0] = make_v(c0.x, c0.y, c0.z, c0.w, q2x[g], q2y[g], q2z[g]);
            vv[1] = make_v(c1.x, c1.y, c1.z, c1.w, q2x[g], q2y[g], q2z[g]);
            vv[2] = make_v(c2.x, c2.y, c2.z, c2.w, q2x[g], q2y[g], q2z[g]);
            vv[3] = make_v(c3.x, c3.y, c3.z, c3.w, q2x[g], q2y[g], q2z[g]);
#pragma unroll
            for (int i = 0; i < 4; ++i) {
                if (vv[i] <= vthr[g]) {  // rare divergent branch
                    float d = __fadd_rn(vv[i], qn[g]);  // exact reference d
                    if (d <= tau_d[g]) {
                        int pos = atomicAdd(&cnt_lds[wib][g], 1);
                        if (pos < 128)
                            buf[wib][g][pos] =
                                ((unsigned long long)sortable(d) << 32) | (unsigned)(nb + i * 64);
                    }
                }
            }
        }
    }
    __syncthreads();

#pragma unroll
    for (int g = 0; g < G; ++g) {
        int cnt = cnt_lds[wib][g];
        int* my_ind = ind + ((size_t)b * S + sbase + g) * K;
        if (cnt >= K && cnt <= 128) {
            int lim = cnt < 64 ? cnt : 64;
            unsigned long long a = (lane < lim) ? buf[wib][g][lane] : ~0ull;
            a = bitonic_sort64_u64(a, lane);
            unsigned long long c = a;
            if (cnt > 64) {
                unsigned long long bk = (64 + lane < cnt) ? buf[wib][g][64 + lane] : ~0ull;
                bk = bitonic_sort64_u64(bk, lane);
                unsigned long long brev = __shfl(bk, 63 - lane, 64);
                c = a < brev ? a : brev;  // lower half of 64+64 merge
#pragma unroll
                for (int j = 32; j > 0; j >>= 1) {
                    unsigned long long o = __shfl_xor(c, j, 64);
                    bool keepmin = (lane & j) == 0;
                    c = ((c < o) == keepmin) ? c : o;
                }
            }
            if (lane < K) my_ind[lane] = (int)(unsigned)c;
        } else {
            // Exact fallback (never expected): full per-wave rescan.
            float qx = 0.5f * q2x[g], qy = 0.5f * q2y[g], qz = 0.5f * q2z[g];
            unsigned long long a[K];
#pragma unroll
            for (int i = 0; i < K; ++i) a[i] = ~0ull;
            for (int n = lane; n < N; n += 64) {
                float4 c = P4[n];
                float d = make_d(c.x, c.y, c.z, c.w, qx, qy, qz, qn[g]);
                unsigned long long key = ((unsigned long long)sortable(d) << 32) | (unsigned)n;
                if (key < a[K - 1]) {
#pragma unroll
                    for (int i = K - 1; i >= 1; --i) {
                        unsigned long long lo = a[i - 1];
                        a[i] = key < lo ? lo : (key < a[i] ? key : a[i]);
                    }
                    a[0] = key < a[0] ? key : a[0];
                }
            }
            for (int r = 0; r < K; ++r) {
                unsigned long long best = a[0];
#pragma unroll
                for (int mm = 1; mm < 64; mm <<= 1) {
                    unsigned long long o = __shfl_xor(best, mm, 64);
                    best = o < best ? o : best;
                }
                if (lane == 0) my_ind[r] = (int)(unsigned)best;
                bool won = (a[0] == best);
#pragma unroll
                for (int i = 0; i < K - 1; ++i) a[i] = won ? a[i + 1] : a[i];
                a[K - 1] = won ? ~0ull : a[K - 1];
            }
        }
    }
}

// ===== gather: LDS-staged tile (verified R17) =====
__global__ void __launch_bounds__(256) gather_tile_kernel(const float4* __restrict__ pts4,
                                                          const float* __restrict__ newp,
                                                          const float* __restrict__ featT,
                                                          const int* __restrict__ ind,
                                                          float* __restrict__ out) {
    __shared__ float tile[64][69];
    int bid = blockIdx.x;
    int b = bid >> 9;
    int k = (bid >> 5) & (K - 1);
    int s0 = (bid & 31) << 6;
    int j = threadIdx.x >> 2;
    int p = threadIdx.x & 3;
    int s = s0 + j;
    int id = ind[((size_t)b * S + s) * K + k];
    const float* row = featT + ((size_t)b * N + id) * D;
#pragma unroll
    for (int i = 0; i < 4; ++i) {
        int f = p + 4 * i;
        float4 v = *(const float4*)(row + f * 4);
        *(float4*)(&tile[j][3 + f * 4]) = v;
    }
    if (p == 0) {
        float4 pt = pts4[(size_t)b * N + id];
        const float* Q = newp + (size_t)b * 3 * S;
        tile[j][0] = __fsub_rn(pt.x, Q[s]);
        tile[j][1] = __fsub_rn(pt.y, Q[S + s]);
        tile[j][2] = __fsub_rn(pt.z, Q[2 * S + s]);
    }
    __syncthreads();
    size_t KS = (size_t)K * S;
    float* ob = out + ((size_t)b * C * K + k) * S + s0;
#pragma unroll
    for (int it = 0; it < 17; ++it) {
        int c = it * 4 + (threadIdx.x >> 6);
        int l = threadIdx.x & 63;
        if (c < C) ob[(size_t)c * KS + l] = tile[l][c];
    }
}

// Fallback gather (no featT workspace)
__global__ void __launch_bounds__(256) gather_kernel(const float4* __restrict__ pts4,
                                                     const float* __restrict__ newp,
                                                     const float* __restrict__ feat,
                                                     const int* __restrict__ ind,
                                                     float* __restrict__ out) {
    int t = blockIdx.x * blockDim.x + threadIdx.x;
    int s = t & (S - 1);
    int k = (t >> 11) & (K - 1);
    int rest = t >> 15;
    int g = rest % 17;
    int b = rest / 17;
    if (b >= B) return;
    int id = ind[((size_t)b * S + s) * K + k];
    size_t KS = (size_t)K * S;
    if (g == 0) {
        float4 p = pts4[(size_t)b * N + id];
        const float* Q = newp + (size_t)b * 3 * S;
        float* o = out + ((size_t)b * C * K + k) * S + s;
        o[0] = __fsub_rn(p.x, Q[s]);
        o[KS] = __fsub_rn(p.y, Q[S + s]);
        o[2 * KS] = __fsub_rn(p.z, Q[2 * S + s]);
    } else {
        int cb = (g - 1) * 4;
        const float* F = feat + (size_t)b * D * N;
        float4 f = make_float4(F[(size_t)cb * N + id], F[(size_t)(cb + 1) * N + id],
                               F[(size_t)(cb + 2) * N + id], F[(size_t)(cb + 3) * N + id]);
        float* o = out + (((size_t)b * C + 3 + cb) * K + k) * S + s;
        o[0] = f.x;
        o[KS] = f.y;
        o[2 * KS] = f.z;
        o[3 * KS] = f.w;
    }
}

extern "C" void kernel_launch(void* const* d_in, const int* in_sizes, int n_in,
                              void* d_out, int out_size, void* d_ws, size_t ws_size,
                              hipStream_t stream) {
    const float* pts = (const float*)d_in[0];   // [B, 3, N]
    const float* newp = (const float*)d_in[1];  // [B, 3, S]
    const float* feat = (const float*)d_in[2];  // [B, D, N]
    float* out = (float*)d_out;                 // [B, C, K, S]

    size_t off = 0;
    int* ind = (int*)((char*)d_ws + off);           off += (size_t)B * S * K * sizeof(int);
    float4* pts4 = (float4*)((char*)d_ws + off);    off += (size_t)B * N * sizeof(float4);
    float4* binned = (float4*)((char*)d_ws + off);  off += (size_t)B * N * sizeof(float4);
    int* counts = (int*)((char*)d_ws + off);        off += (size_t)B * CELLS * sizeof(int);
    int* cursor = (int*)((char*)d_ws + off);        off += (size_t)B * CELLS * sizeof(int);
    int* starts = (int*)((char*)d_ws + off);        off += (size_t)B * (CELLS + 1) * sizeof(int);
    float* tau = (float*)((char*)d_ws + off);       off += (size_t)B * S * sizeof(float);
    float* featT = (float*)((char*)d_ws + off);
    size_t need = off + (size_t)B * N * D * sizeof(float);
    int useT = (ws_size >= need) ? 1 : 0;

    zero_kernel<<<(B * CELLS + 255) / 256, 256, 0, stream>>>(counts);
    pack_kernel<<<(B * N) / 256, 256, 0, stream>>>(pts, pts4, counts);
    prefix_kernel<<<B, 1024, 0, stream>>>(counts, starts, cursor);
    scatter_kernel<<<(B * N) / 256, 256, 0, stream>>>(pts4, cursor, binned);
    tau_kernel<<<(B * S) / 4, 256, 0, stream>>>(binned, starts, newp, tau);
    if (useT) transpose_kernel<<<B * (N / 64), 256, 0, stream>>>(feat, featT);
    knn_kernel<<<(B * S) / (G * 4), 256, 0, stream>>>(pts4, newp, tau, ind);
    if (useT)
        gather_tile_kernel<<<B * K * (S / 64), 256, 0, stream>>>(pts4, newp, featT, ind, out);
    else
        gather_kernel<<<(B * 17 * K * S) / 256, 256, 0, stream>>>(pts4, newp, feat, ind, out);
}

// Round 20
// 209.053 us; speedup vs baseline: 2.5101x; 1.4072x over previous
//
#include <hip/hip_runtime.h>

constexpr int B = 8, N = 8192, S = 2048, D = 64, K = 16, C = 3 + D;
constexpr int G = 4;        // queries per wave (knn)
constexpr int GD = 16;      // grid cells per axis
constexpr int CELLS = GD * GD * GD;

__device__ __forceinline__ unsigned sortable(float f) {
    unsigned u = __float_as_uint(f);
    unsigned mask = (unsigned)(((int)u) >> 31) | 0x80000000u;
    return u ^ mask;
}

__device__ __forceinline__ float uload(const float* p) {
    return __uint_as_float(__builtin_amdgcn_readfirstlane(__float_as_uint(*p)));
}

// Scalar reference-exact distance (fallback path): dot asc-FMA, d=(pn-2dot)+qn [R8]
__device__ __forceinline__ float make_d(float px, float py, float pz, float pnv,
                                        float qx, float qy, float qz, float qn) {
    float dot = __fmaf_rn(pz, qz, __fmaf_rn(py, qy, __fmul_rn(px, qx)));
    return __fadd_rn(__fsub_rn(pnv, __fmul_rn(2.0f, dot)), qn);
}

// EXACT v = pn - dot2; dot2 == 2*dot bitwise (pow-2 scale commutes with rounding)
__device__ __forceinline__ float make_v(float px, float py, float pz, float pnv,
                                        float q2x, float q2y, float q2z) {
    float dot2 = __fmaf_rn(pz, q2z, __fmaf_rn(py, q2y, __fmul_rn(px, q2x)));
    return __fsub_rn(pnv, dot2);
}

__device__ __forceinline__ int cell_of(float x) {
    int c = (int)floorf(__fmul_rn(__fadd_rn(x, 4.0f), 2.0f));
    return c < 0 ? 0 : (c > GD - 1 ? GD - 1 : c);
}

__device__ __forceinline__ float bitonic_sort64_f32(float v, int lane) {
#pragma unroll
    for (int k = 2; k <= 64; k <<= 1)
#pragma unroll
        for (int j = k >> 1; j > 0; j >>= 1) {
            float o = __shfl_xor(v, j, 64);
            bool keepmin = ((lane & k) == 0) == ((lane & j) == 0);
            float mn = fminf(v, o), mx = fmaxf(v, o);
            v = keepmin ? mn : mx;
        }
    return v;
}

__device__ __forceinline__ unsigned long long bitonic_sort64_u64(unsigned long long v, int lane) {
#pragma unroll
    for (int k = 2; k <= 64; k <<= 1)
#pragma unroll
        for (int j = k >> 1; j > 0; j >>= 1) {
            unsigned long long o = __shfl_xor(v, j, 64);
            bool keepmin = ((lane & k) == 0) == ((lane & j) == 0);
            v = ((v < o) == keepmin) ? v : o;
        }
    return v;
}

__global__ void zero_kernel(int* counts) {
    int t = blockIdx.x * blockDim.x + threadIdx.x;
    if (t < B * CELLS) counts[t] = 0;
}

// pts4[b][n] = {x,y,z,||p||^2} (desc no-FMA norm, verified R8) + fused histogram
__global__ void pack_kernel(const float* __restrict__ pts, float4* __restrict__ pts4,
                            int* __restrict__ counts) {
    int t = blockIdx.x * blockDim.x + threadIdx.x;
    if (t >= B * N) return;
    int b = t >> 13, n = t & (N - 1);
    const float* P = pts + (size_t)b * 3 * N;
    float x = P[n], y = P[N + n], z = P[2 * N + n];
    float pn = __fadd_rn(__fadd_rn(__fmul_rn(z, z), __fmul_rn(y, y)), __fmul_rn(x, x));
    pts4[t] = make_float4(x, y, z, pn);
    int cid = (cell_of(z) * GD + cell_of(y)) * GD + cell_of(x);
    atomicAdd(&counts[b * CELLS + cid], 1);
}

// Per-batch exclusive prefix over 4096 cell counts; writes starts (+sentinel) and cursor.
__global__ void __launch_bounds__(1024) prefix_kernel(const int* __restrict__ counts,
                                                      int* __restrict__ starts,
                                                      int* __restrict__ cursor) {
    __shared__ int sdata[1024];
    int b = blockIdx.x, t = threadIdx.x;
    const int* cb = counts + b * CELLS;
    int c0 = t * 4;
    int l0 = cb[c0], l1 = cb[c0 + 1], l2 = cb[c0 + 2], l3 = cb[c0 + 3];
    int mysum = l0 + l1 + l2 + l3;
    sdata[t] = mysum;
    __syncthreads();
    for (int off = 1; off < 1024; off <<= 1) {
        int v = (t >= off) ? sdata[t - off] : 0;
        __syncthreads();
        sdata[t] += v;
        __syncthreads();
    }
    int excl = sdata[t] - mysum;
    int* sb = starts + b * (CELLS + 1);
    int* ub = cursor + b * CELLS;
    sb[c0] = excl;                 ub[c0] = excl;
    sb[c0 + 1] = excl + l0;        ub[c0 + 1] = excl + l0;
    sb[c0 + 2] = excl + l0 + l1;   ub[c0 + 2] = excl + l0 + l1;
    sb[c0 + 3] = excl + l0 + l1 + l2; ub[c0 + 3] = excl + l0 + l1 + l2;
    if (t == 1023) sb[CELLS] = N;
}

// Counting-sort scatter: binned[b] = pts4[b] grouped by cell.
__global__ void scatter_kernel(const float4* __restrict__ pts4, int* __restrict__ cursor,
                               float4* __restrict__ binned) {
    int t = blockIdx.x * blockDim.x + threadIdx.x;
    if (t >= B * N) return;
    int b = t >> 13;
    float4 c = pts4[t];
    int cid = (cell_of(c.z) * GD + cell_of(c.y)) * GD + cell_of(c.x);
    int pos = atomicAdd(&cursor[b * CELLS + cid], 1);
    binned[(size_t)b * N + pos] = c;
}

// One WAVE per query. Box levels r={1,2,4,16}; per level, iterate (z,y) rows as
// CONTIGUOUS x-segments (2 scalar st[] loads per row, no per-cell walk), with
// the query's own (cz,cy) row FIRST so the 128-cap keeps the nearest witnesses.
// Escalate while < 64 witnesses. tau = 16th-smallest exact d of collected set
// (>=64, <=128 distinct points) => provably >= global d16; tight (local set).
__global__ void __launch_bounds__(256) tau_kernel(const float4* __restrict__ binned,
                                                  const int* __restrict__ starts,
                                                  const float* __restrict__ newp,
                                                  float* __restrict__ tau) {
    __shared__ float dbuf[4][128];
    int wib = threadIdx.x >> 6;
    int lane = threadIdx.x & 63;
    int qid = blockIdx.x * 4 + wib;  // b*S + s
    int b = qid >> 11, s = qid & (S - 1);
    const float* Q = newp + (size_t)b * 3 * S;
    float qx = uload(Q + s), qy = uload(Q + S + s), qz = uload(Q + 2 * S + s);
    float qn = __fadd_rn(__fadd_rn(__fmul_rn(qz, qz), __fmul_rn(qy, qy)), __fmul_rn(qx, qx));
    float q2x = 2.0f * qx, q2y = 2.0f * qy, q2z = 2.0f * qz;
    int cx = cell_of(qx), cy = cell_of(qy), cz = cell_of(qz);
    const float4* P = binned + (size_t)b * N;
    const int* st = starts + b * (CELLS + 1);
    int cnt = 0;
    const int levels[4] = {1, 2, 4, 16};
#pragma unroll 1
    for (int li = 0; li < 4; ++li) {
        if (li > 0 && cnt >= 64) break;
        int r = levels[li];
        cnt = 0;
        int zlo = cz - r < 0 ? 0 : cz - r, zhi = cz + r > GD - 1 ? GD - 1 : cz + r;
        int ylo = cy - r < 0 ? 0 : cy - r, yhi = cy + r > GD - 1 ? GD - 1 : cy + r;
        int xlo = cx - r < 0 ? 0 : cx - r, xhi = cx + r > GD - 1 ? GD - 1 : cx + r;
        // pass 0: center row (cz,cy) only; pass 1: all other rows
#pragma unroll 1
        for (int pass = 0; pass < 2 && cnt < 128; ++pass) {
#pragma unroll 1
            for (int z = zlo; z <= zhi && cnt < 128; ++z) {
#pragma unroll 1
                for (int y = ylo; y <= yhi && cnt < 128; ++y) {
                    bool center = (z == cz) && (y == cy);
                    if ((pass == 0) != center) continue;
                    int rowbase = (z * GD + y) * GD;
                    int p0 = st[rowbase + xlo];
                    int p1 = st[rowbase + xhi + 1];
                    int mcnt = p1 - p0;
                    for (int base = 0; base < mcnt; base += 64) {
                        int idx = base + lane;
                        if (idx < mcnt && cnt + idx < 128) {
                            float4 c = P[p0 + idx];
                            float v = make_v(c.x, c.y, c.z, c.w, q2x, q2y, q2z);
                            dbuf[wib][cnt + idx] = __fadd_rn(v, qn);  // exact scheme d
                        }
                    }
                    cnt += mcnt;
                    if (cnt > 128) cnt = 128;
                }
            }
        }
    }
    float a = (lane < cnt) ? dbuf[wib][lane] : __int_as_float(0x7f800000);
    a = bitonic_sort64_f32(a, lane);
    float tv;
    if (cnt > 64) {
        float bk = (64 + lane < cnt) ? dbuf[wib][64 + lane] : __int_as_float(0x7f800000);
        bk = bitonic_sort64_f32(bk, lane);
        float brev = __shfl(bk, 63 - lane, 64);
        float cmin = fminf(a, brev);  // lower half of 64+64 bitonic merge
#pragma unroll
        for (int j = 32; j > 0; j >>= 1) {
            float o = __shfl_xor(cmin, j, 64);
            bool keepmin = (lane & j) == 0;
            float mn = fminf(cmin, o), mx = fmaxf(cmin, o);
            cmin = keepmin ? mn : mx;
        }
        tv = __shfl(cmin, 15, 64);
    } else {
        tv = __shfl(a, 15, 64);
    }
    if (lane == 0) tau[qid] = tv;
}

// feat [B][D][N] -> featT [B][N][D], LDS-tiled 64x64
__global__ void __launch_bounds__(256) transpose_kernel(const float* __restrict__ feat,
                                                        float* __restrict__ featT) {
    __shared__ float tile[64][65];
    int b = blockIdx.x >> 7;
    int n0 = (blockIdx.x & 127) << 6;
    int col = threadIdx.x & 63;
    int crow = threadIdx.x >> 6;
    const float* F = feat + (size_t)b * D * N;
#pragma unroll
    for (int i = 0; i < 16; ++i) {
        int c = i * 4 + crow;
        tile[c][col] = F[(size_t)c * N + n0 + col];
    }
    __syncthreads();
    float* FT = featT + ((size_t)b * N + n0) * D;
#pragma unroll
    for (int i = 0; i < 16; ++i) {
        int nl = i * 4 + crow;
        FT[(size_t)nl * D + col] = tile[col][nl];
    }
}

// knn: single scan with precomputed tau (R18/R19-verified logic).
__global__ void __launch_bounds__(256) knn_kernel(const float4* __restrict__ pts4,
                                                  const float* __restrict__ newp,
                                                  const float* __restrict__ tau,
                                                  int* __restrict__ ind) {
    __shared__ unsigned long long buf[4][G][128];
    __shared__ int cnt_lds[4][G];
    int wib = threadIdx.x >> 6;
    int lane = threadIdx.x & 63;
    int wid = blockIdx.x * 4 + wib;
    int b = wid >> 9;
    int sbase = (wid & 511) * G;
    const float4* P4 = pts4 + (size_t)b * N;
    const float* Q = newp + (size_t)b * 3 * S;
    if (lane < G) cnt_lds[wib][lane] = 0;
    float qn[G], q2x[G], q2y[G], q2z[G], tau_d[G], vthr[G];
#pragma unroll
    for (int g = 0; g < G; ++g) {
        int s = sbase + g;
        float qx = uload(Q + s), qy = uload(Q + S + s), qz = uload(Q + 2 * S + s);
        qn[g] = __fadd_rn(__fadd_rn(__fmul_rn(qz, qz), __fmul_rn(qy, qy)), __fmul_rn(qx, qx));
        q2x[g] = 2.0f * qx;
        q2y[g] = 2.0f * qy;
        q2z[g] = 2.0f * qz;
        tau_d[g] = uload(tau + (b << 11) + s);  // exact-witness bound >= d16
        vthr[g] = __fadd_rn(__fsub_rn(tau_d[g], qn[g]), 1e-4f);  // superset prefilter
    }

    for (int blk = 0; blk < N / 256; ++blk) {
        int nb = blk * 256 + lane;
        float4 c0 = P4[nb], c1 = P4[nb + 64], c2 = P4[nb + 128], c3 = P4[nb + 192];
#pragma unroll
        for (int g = 0; g < G; ++g) {
            float vv[4];
            vv[0] = make_v(c0.x, c0.y, c0.z, c0.w, q2x[g], q2y[g], q2z[g]);
            vv[1] = make_v(c1.x, c1.y, c1.z, c1.w, q2x[g], q2y[g], q2z[g]);
            vv[2] = make_v(c2.x, c2.y, c2.z, c2.w, q2x[g], q2y[g], q2z[g]);
            vv[3] = make_v(c3.x, c3.y, c3.z, c3.w, q2x[g], q2y[g], q2z[g]);
#pragma unroll
            for (int i = 0; i < 4; ++i) {
                if (vv[i] <= vthr[g]) {  // rare divergent branch
                    float d = __fadd_rn(vv[i], qn[g]);  // exact reference d
                    if (d <= tau_d[g]) {
                        int pos = atomicAdd(&cnt_lds[wib][g], 1);
                        if (pos < 128)
                            buf[wib][g][pos] =
                                ((unsigned long long)sortable(d) << 32) | (unsigned)(nb + i * 64);
                    }
                }
            }
        }
    }
    __syncthreads();

#pragma unroll
    for (int g = 0; g < G; ++g) {
        int cnt = cnt_lds[wib][g];
        int* my_ind = ind + ((size_t)b * S + sbase + g) * K;
        if (cnt >= K && cnt <= 128) {
            int lim = cnt < 64 ? cnt : 64;
            unsigned long long a = (lane < lim) ? buf[wib][g][lane] : ~0ull;
            a = bitonic_sort64_u64(a, lane);
            unsigned long long c = a;
            if (cnt > 64) {
                unsigned long long bk = (64 + lane < cnt) ? buf[wib][g][64 + lane] : ~0ull;
                bk = bitonic_sort64_u64(bk, lane);
                unsigned long long brev = __shfl(bk, 63 - lane, 64);
                c = a < brev ? a : brev;  // lower half of 64+64 merge
#pragma unroll
                for (int j = 32; j > 0; j >>= 1) {
                    unsigned long long o = __shfl_xor(c, j, 64);
                    bool keepmin = (lane & j) == 0;
                    c = ((c < o) == keepmin) ? c : o;
                }
            }
            if (lane < K) my_ind[lane] = (int)(unsigned)c;
        } else {
            // Exact fallback (now ~never taken): full per-wave rescan.
            float qx = 0.5f * q2x[g], qy = 0.5f * q2y[g], qz = 0.5f * q2z[g];
            unsigned long long a[K];
#pragma unroll
            for (int i = 0; i < K; ++i) a[i] = ~0ull;
            for (int n = lane; n < N; n += 64) {
                float4 c = P4[n];
                float d = make_d(c.x, c.y, c.z, c.w, qx, qy, qz, qn[g]);
                unsigned long long key = ((unsigned long long)sortable(d) << 32) | (unsigned)n;
                if (key < a[K - 1]) {
#pragma unroll
                    for (int i = K - 1; i >= 1; --i) {
                        unsigned long long lo = a[i - 1];
                        a[i] = key < lo ? lo : (key < a[i] ? key : a[i]);
                    }
                    a[0] = key < a[0] ? key : a[0];
                }
            }
            for (int r = 0; r < K; ++r) {
                unsigned long long best = a[0];
#pragma unroll
                for (int mm = 1; mm < 64; mm <<= 1) {
                    unsigned long long o = __shfl_xor(best, mm, 64);
                    best = o < best ? o : best;
                }
                if (lane == 0) my_ind[r] = (int)(unsigned)best;
                bool won = (a[0] == best);
#pragma unroll
                for (int i = 0; i < K - 1; ++i) a[i] = won ? a[i + 1] : a[i];
                a[K - 1] = won ? ~0ull : a[K - 1];
            }
        }
    }
}

// ===== gather: LDS-staged tile (verified R17) =====
__global__ void __launch_bounds__(256) gather_tile_kernel(const float4* __restrict__ pts4,
                                                          const float* __restrict__ newp,
                                                          const float* __restrict__ featT,
                                                          const int* __restrict__ ind,
                                                          float* __restrict__ out) {
    __shared__ float tile[64][69];
    int bid = blockIdx.x;
    int b = bid >> 9;
    int k = (bid >> 5) & (K - 1);
    int s0 = (bid & 31) << 6;
    int j = threadIdx.x >> 2;
    int p = threadIdx.x & 3;
    int s = s0 + j;
    int id = ind[((size_t)b * S + s) * K + k];
    const float* row = featT + ((size_t)b * N + id) * D;
#pragma unroll
    for (int i = 0; i < 4; ++i) {
        int f = p + 4 * i;
        float4 v = *(const float4*)(row + f * 4);
        *(float4*)(&tile[j][3 + f * 4]) = v;
    }
    if (p == 0) {
        float4 pt = pts4[(size_t)b * N + id];
        const float* Q = newp + (size_t)b * 3 * S;
        tile[j][0] = __fsub_rn(pt.x, Q[s]);
        tile[j][1] = __fsub_rn(pt.y, Q[S + s]);
        tile[j][2] = __fsub_rn(pt.z, Q[2 * S + s]);
    }
    __syncthreads();
    size_t KS = (size_t)K * S;
    float* ob = out + ((size_t)b * C * K + k) * S + s0;
#pragma unroll
    for (int it = 0; it < 17; ++it) {
        int c = it * 4 + (threadIdx.x >> 6);
        int l = threadIdx.x & 63;
        if (c < C) ob[(size_t)c * KS + l] = tile[l][c];
    }
}

// Fallback gather (no featT workspace)
__global__ void __launch_bounds__(256) gather_kernel(const float4* __restrict__ pts4,
                                                     const float* __restrict__ newp,
                                                     const float* __restrict__ feat,
                                                     const int* __restrict__ ind,
                                                     float* __restrict__ out) {
    int t = blockIdx.x * blockDim.x + threadIdx.x;
    int s = t & (S - 1);
    int k = (t >> 11) & (K - 1);
    int rest = t >> 15;
    int g = rest % 17;
    int b = rest / 17;
    if (b >= B) return;
    int id = ind[((size_t)b * S + s) * K + k];
    size_t KS = (size_t)K * S;
    if (g == 0) {
        float4 p = pts4[(size_t)b * N + id];
        const float* Q = newp + (size_t)b * 3 * S;
        float* o = out + ((size_t)b * C * K + k) * S + s;
        o[0] = __fsub_rn(p.x, Q[s]);
        o[KS] = __fsub_rn(p.y, Q[S + s]);
        o[2 * KS] = __fsub_rn(p.z, Q[2 * S + s]);
    } else {
        int cb = (g - 1) * 4;
        const float* F = feat + (size_t)b * D * N;
        float4 f = make_float4(F[(size_t)cb * N + id], F[(size_t)(cb + 1) * N + id],
                               F[(size_t)(cb + 2) * N + id], F[(size_t)(cb + 3) * N + id]);
        float* o = out + (((size_t)b * C + 3 + cb) * K + k) * S + s;
        o[0] = f.x;
        o[KS] = f.y;
        o[2 * KS] = f.z;
        o[3 * KS] = f.w;
    }
}

extern "C" void kernel_launch(void* const* d_in, const int* in_sizes, int n_in,
                              void* d_out, int out_size, void* d_ws, size_t ws_size,
                              hipStream_t stream) {
    const float* pts = (const float*)d_in[0];   // [B, 3, N]
    const float* newp = (const float*)d_in[1];  // [B, 3, S]
    const float* feat = (const float*)d_in[2];  // [B, D, N]
    float* out = (float*)d_out;                 // [B, C, K, S]

    size_t off = 0;
    int* ind = (int*)((char*)d_ws + off);           off += (size_t)B * S * K * sizeof(int);
    float4* pts4 = (float4*)((char*)d_ws + off);    off += (size_t)B * N * sizeof(float4);
    float4* binned = (float4*)((char*)d_ws + off);  off += (size_t)B * N * sizeof(float4);
    int* counts = (int*)((char*)d_ws + off);        off += (size_t)B * CELLS * sizeof(int);
    int* cursor = (int*)((char*)d_ws + off);        off += (size_t)B * CELLS * sizeof(int);
    int* starts = (int*)((char*)d_ws + off);        off += (size_t)B * (CELLS + 1) * sizeof(int);
    float* tau = (float*)((char*)d_ws + off);       off += (size_t)B * S * sizeof(float);
    float* featT = (float*)((char*)d_ws + off);
    size_t need = off + (size_t)B * N * D * sizeof(float);
    int useT = (ws_size >= need) ? 1 : 0;

    zero_kernel<<<(B * CELLS + 255) / 256, 256, 0, stream>>>(counts);
    pack_kernel<<<(B * N) / 256, 256, 0, stream>>>(pts, pts4, counts);
    prefix_kernel<<<B, 1024, 0, stream>>>(counts, starts, cursor);
    scatter_kernel<<<(B * N) / 256, 256, 0, stream>>>(pts4, cursor, binned);
    tau_kernel<<<(B * S) / 4, 256, 0, stream>>>(binned, starts, newp, tau);
    if (useT) transpose_kernel<<<B * (N / 64), 256, 0, stream>>>(feat, featT);
    knn_kernel<<<(B * S) / (G * 4), 256, 0, stream>>>(pts4, newp, tau, ind);
    if (useT)
        gather_tile_kernel<<<B * K * (S / 64), 256, 0, stream>>>(pts4, newp, featT, ind, out);
    else
        gather_kernel<<<(B * 17 * K * S) / 256, 256, 0, stream>>>(pts4, newp, feat, ind, out);
}

// Round 21
// 124.195 us; speedup vs baseline: 4.2252x; 1.6833x over previous
//
#include <hip/hip_runtime.h>

constexpr int B = 8, N = 8192, S = 2048, D = 64, K = 16, C = 3 + D;
constexpr int G = 4;      // queries per wave
constexpr int M = 2048;   // tau subsample size (first M points)
constexpr int BUFD = 192; // collection buffer depth (E[cnt]=64, P(>192)~e-14)

__device__ __forceinline__ unsigned sortable(float f) {
    unsigned u = __float_as_uint(f);
    unsigned mask = (unsigned)(((int)u) >> 31) | 0x80000000u;
    return u ^ mask;
}

__device__ __forceinline__ float uload(const float* p) {
    return __uint_as_float(__builtin_amdgcn_readfirstlane(__float_as_uint(*p)));
}

// Scalar reference-exact distance (fallback path): dot asc-FMA, d=(pn-2dot)+qn [R8]
__device__ __forceinline__ float make_d(float px, float py, float pz, float pnv,
                                        float qx, float qy, float qz, float qn) {
    float dot = __fmaf_rn(pz, qz, __fmaf_rn(py, qy, __fmul_rn(px, qx)));
    return __fadd_rn(__fsub_rn(pnv, __fmul_rn(2.0f, dot)), qn);
}

// EXACT v = pn - dot2; dot2 == 2*dot bitwise (pow-2 scale commutes with rounding)
__device__ __forceinline__ float make_v(float px, float py, float pz, float pnv,
                                        float q2x, float q2y, float q2z) {
    float dot2 = __fmaf_rn(pz, q2z, __fmaf_rn(py, q2y, __fmul_rn(px, q2x)));
    return __fsub_rn(pnv, dot2);
}

__device__ __forceinline__ float bitonic_sort64_f32(float v, int lane) {
#pragma unroll
    for (int k = 2; k <= 64; k <<= 1)
#pragma unroll
        for (int j = k >> 1; j > 0; j >>= 1) {
            float o = __shfl_xor(v, j, 64);
            bool keepmin = ((lane & k) == 0) == ((lane & j) == 0);
            float mn = fminf(v, o), mx = fmaxf(v, o);
            v = keepmin ? mn : mx;
        }
    return v;
}

// pts4[b][n] = {x, y, z, ||p||^2}; norm = (z*z + y*y) + x*x desc no-FMA [verified R8]
__global__ void pack_kernel(const float* __restrict__ pts, float4* __restrict__ pts4) {
    int t = blockIdx.x * blockDim.x + threadIdx.x;
    if (t >= B * N) return;
    int b = t >> 13, n = t & (N - 1);
    const float* P = pts + (size_t)b * 3 * N;
    float x = P[n], y = P[N + n], z = P[2 * N + n];
    float pn = __fadd_rn(__fadd_rn(__fmul_rn(z, z), __fmul_rn(y, y)), __fmul_rn(x, x));
    pts4[t] = make_float4(x, y, z, pn);
}

// feat [B][D][N] -> featT [B][N][D], LDS-tiled 64x64
__global__ void __launch_bounds__(256) transpose_kernel(const float* __restrict__ feat,
                                                        float* __restrict__ featT) {
    __shared__ float tile[64][65];
    int b = blockIdx.x >> 7;
    int n0 = (blockIdx.x & 127) << 6;
    int col = threadIdx.x & 63;
    int crow = threadIdx.x >> 6;
    const float* F = feat + (size_t)b * D * N;
#pragma unroll
    for (int i = 0; i < 16; ++i) {
        int c = i * 4 + crow;
        tile[c][col] = F[(size_t)c * N + n0 + col];
    }
    __syncthreads();
    float* FT = featT + ((size_t)b * N + n0) * D;
#pragma unroll
    for (int i = 0; i < 16; ++i) {
        int nl = i * 4 + crow;
        FT[(size_t)nl * D + col] = tile[col][nl];
    }
}

// One wave per G=4 queries. Pass 1 (subsample): per-lane min of v over the
// FIRST M=2048 points (L1-resident, every wave reads the same 32KB); tau_v =
// 16th-smallest lane-min => 16 distinct witnesses with v <= tau_v; tau_d =
// rn(tau_v + qn) >= their d => >= global d16-upper-bound... (valid threshold).
// Pass 2 (full): prefilter v <= vthr (superset of d <= tau_d), exact d check,
// LDS-atomic compact into 192 slots (E[cnt]=64). Selection: 16 rounds of
// 3-slot wave pop-min on exact (d,idx) u64 keys (ascending, tie -> lower idx).
__global__ void __launch_bounds__(256) knn_kernel(const float4* __restrict__ pts4,
                                                  const float* __restrict__ newp,
                                                  int* __restrict__ ind) {
    __shared__ unsigned long long buf[4][G][BUFD];
    __shared__ int cnt_lds[4][G];
    int wib = threadIdx.x >> 6;
    int lane = threadIdx.x & 63;
    int wid = blockIdx.x * 4 + wib;
    int b = wid >> 9;
    int sbase = (wid & 511) * G;
    const float4* P4 = pts4 + (size_t)b * N;
    const float* Q = newp + (size_t)b * 3 * S;
    if (lane < G) cnt_lds[wib][lane] = 0;
    float qn[G], q2x[G], q2y[G], q2z[G];
#pragma unroll
    for (int g = 0; g < G; ++g) {
        int s = sbase + g;
        float qx = uload(Q + s), qy = uload(Q + S + s), qz = uload(Q + 2 * S + s);
        qn[g] = __fadd_rn(__fadd_rn(__fmul_rn(qz, qz), __fmul_rn(qy, qy)), __fmul_rn(qx, qx));
        q2x[g] = 2.0f * qx;  // exact pow-2 scale
        q2y[g] = 2.0f * qy;
        q2z[g] = 2.0f * qz;
    }

    // ---- pass 1: per-lane min of v over first M points (32 candidates/lane) ----
    float m[G];
#pragma unroll
    for (int g = 0; g < G; ++g) m[g] = __int_as_float(0x7f800000);
    for (int blk = 0; blk < M / 256; ++blk) {
        int nb = blk * 256 + lane;
        float4 c0 = P4[nb], c1 = P4[nb + 64], c2 = P4[nb + 128], c3 = P4[nb + 192];
#pragma unroll
        for (int g = 0; g < G; ++g) {
            float v0 = make_v(c0.x, c0.y, c0.z, c0.w, q2x[g], q2y[g], q2z[g]);
            float v1 = make_v(c1.x, c1.y, c1.z, c1.w, q2x[g], q2y[g], q2z[g]);
            float v2 = make_v(c2.x, c2.y, c2.z, c2.w, q2x[g], q2y[g], q2z[g]);
            float v3 = make_v(c3.x, c3.y, c3.z, c3.w, q2x[g], q2y[g], q2z[g]);
            m[g] = fminf(m[g], fminf(fminf(v0, v1), fminf(v2, v3)));
        }
    }
    float tau_d[G], vthr[G];
#pragma unroll
    for (int g = 0; g < G; ++g) {
        float tau_v = __shfl(bitonic_sort64_f32(m[g], lane), 15, 64);  // 16 witnesses
        tau_d[g] = __fadd_rn(tau_v, qn[g]);  // valid upper bound on global d16
        vthr[g] = __fadd_rn(__fsub_rn(tau_d[g], qn[g]), 1e-4f);  // superset prefilter
    }

    // ---- pass 2: full scan; prefilter on v, exact d check + LDS-atomic compact ----
    for (int blk = 0; blk < N / 256; ++blk) {
        int nb = blk * 256 + lane;
        float4 c0 = P4[nb], c1 = P4[nb + 64], c2 = P4[nb + 128], c3 = P4[nb + 192];
#pragma unroll
        for (int g = 0; g < G; ++g) {
            float vv[4];
            vv[0] = make_v(c0.x, c0.y, c0.z, c0.w, q2x[g], q2y[g], q2z[g]);
            vv[1] = make_v(c1.x, c1.y, c1.z, c1.w, q2x[g], q2y[g], q2z[g]);
            vv[2] = make_v(c2.x, c2.y, c2.z, c2.w, q2x[g], q2y[g], q2z[g]);
            vv[3] = make_v(c3.x, c3.y, c3.z, c3.w, q2x[g], q2y[g], q2z[g]);
#pragma unroll
            for (int i = 0; i < 4; ++i) {
                if (vv[i] <= vthr[g]) {  // ~0.8% of sites
                    float d = __fadd_rn(vv[i], qn[g]);  // exact reference d
                    if (d <= tau_d[g]) {
                        int pos = atomicAdd(&cnt_lds[wib][g], 1);
                        if (pos < BUFD)
                            buf[wib][g][pos] =
                                ((unsigned long long)sortable(d) << 32) | (unsigned)(nb + i * 64);
                    }
                }
            }
        }
    }
    __syncthreads();

#pragma unroll 1
    for (int g = 0; g < G; ++g) {
        int cnt = cnt_lds[wib][g];
        int* my_ind = ind + ((size_t)b * S + sbase + g) * K;
        if (cnt >= K && cnt <= BUFD) {
            // 3 slots per lane cover up to 192 keys; 16 rounds of wave pop-min.
            unsigned long long a0 = (lane < cnt) ? buf[wib][g][lane] : ~0ull;
            unsigned long long a1 = (64 + lane < cnt) ? buf[wib][g][64 + lane] : ~0ull;
            unsigned long long a2 = (128 + lane < cnt) ? buf[wib][g][128 + lane] : ~0ull;
#pragma unroll 1
            for (int r = 0; r < K; ++r) {
                unsigned long long lm = a0 < a1 ? a0 : a1;
                lm = a2 < lm ? a2 : lm;
                unsigned long long gm = lm;
#pragma unroll
                for (int mm = 1; mm < 64; mm <<= 1) {
                    unsigned long long o = __shfl_xor(gm, mm, 64);
                    gm = o < gm ? o : gm;
                }
                if (lane == 0) my_ind[r] = (int)(unsigned)gm;  // keys unique
                bool w0 = (a0 == gm);
                bool w1 = (a1 == gm) && !w0;
                bool w2 = (a2 == gm) && !(w0 || w1);
                a0 = w0 ? ~0ull : a0;
                a1 = w1 ? ~0ull : a1;
                a2 = w2 ? ~0ull : a2;
            }
        } else {
            // Exact fallback (P ~ e-14 per query): full per-wave rescan.
            float qx = 0.5f * q2x[g], qy = 0.5f * q2y[g], qz = 0.5f * q2z[g];
            unsigned long long a[K];
#pragma unroll
            for (int i = 0; i < K; ++i) a[i] = ~0ull;
            for (int n = lane; n < N; n += 64) {
                float4 c = P4[n];
                float d = make_d(c.x, c.y, c.z, c.w, qx, qy, qz, qn[g]);
                unsigned long long key = ((unsigned long long)sortable(d) << 32) | (unsigned)n;
                if (key < a[K - 1]) {
#pragma unroll
                    for (int i = K - 1; i >= 1; --i) {
                        unsigned long long lo = a[i - 1];
                        a[i] = key < lo ? lo : (key < a[i] ? key : a[i]);
                    }
                    a[0] = key < a[0] ? key : a[0];
                }
            }
            for (int r = 0; r < K; ++r) {
                unsigned long long best = a[0];
#pragma unroll
                for (int mm = 1; mm < 64; mm <<= 1) {
                    unsigned long long o = __shfl_xor(best, mm, 64);
                    best = o < best ? o : best;
                }
                if (lane == 0) my_ind[r] = (int)(unsigned)best;
                bool won = (a[0] == best);
#pragma unroll
                for (int i = 0; i < K - 1; ++i) a[i] = won ? a[i + 1] : a[i];
                a[K - 1] = won ? ~0ull : a[K - 1];
            }
        }
    }
}

// ===== gather: LDS-staged tile (verified R17) =====
__global__ void __launch_bounds__(256) gather_tile_kernel(const float4* __restrict__ pts4,
                                                          const float* __restrict__ newp,
                                                          const float* __restrict__ featT,
                                                          const int* __restrict__ ind,
                                                          float* __restrict__ out) {
    __shared__ float tile[64][69];
    int bid = blockIdx.x;
    int b = bid >> 9;
    int k = (bid >> 5) & (K - 1);
    int s0 = (bid & 31) << 6;
    int j = threadIdx.x >> 2;
    int p = threadIdx.x & 3;
    int s = s0 + j;
    int id = ind[((size_t)b * S + s) * K + k];
    const float* row = featT + ((size_t)b * N + id) * D;
#pragma unroll
    for (int i = 0; i < 4; ++i) {
        int f = p + 4 * i;
        float4 v = *(const float4*)(row + f * 4);
        *(float4*)(&tile[j][3 + f * 4]) = v;
    }
    if (p == 0) {
        float4 pt = pts4[(size_t)b * N + id];
        const float* Q = newp + (size_t)b * 3 * S;
        tile[j][0] = __fsub_rn(pt.x, Q[s]);
        tile[j][1] = __fsub_rn(pt.y, Q[S + s]);
        tile[j][2] = __fsub_rn(pt.z, Q[2 * S + s]);
    }
    __syncthreads();
    size_t KS = (size_t)K * S;
    float* ob = out + ((size_t)b * C * K + k) * S + s0;
#pragma unroll
    for (int it = 0; it < 17; ++it) {
        int c = it * 4 + (threadIdx.x >> 6);
        int l = threadIdx.x & 63;
        if (c < C) ob[(size_t)c * KS + l] = tile[l][c];
    }
}

// Fallback gather (no featT workspace)
__global__ void __launch_bounds__(256) gather_kernel(const float4* __restrict__ pts4,
                                                     const float* __restrict__ newp,
                                                     const float* __restrict__ feat,
                                                     const int* __restrict__ ind,
                                                     float* __restrict__ out) {
    int t = blockIdx.x * blockDim.x + threadIdx.x;
    int s = t & (S - 1);
    int k = (t >> 11) & (K - 1);
    int rest = t >> 15;
    int g = rest % 17;
    int b = rest / 17;
    if (b >= B) return;
    int id = ind[((size_t)b * S + s) * K + k];
    size_t KS = (size_t)K * S;
    if (g == 0) {
        float4 p = pts4[(size_t)b * N + id];
        const float* Q = newp + (size_t)b * 3 * S;
        float* o = out + ((size_t)b * C * K + k) * S + s;
        o[0] = __fsub_rn(p.x, Q[s]);
        o[KS] = __fsub_rn(p.y, Q[S + s]);
        o[2 * KS] = __fsub_rn(p.z, Q[2 * S + s]);
    } else {
        int cb = (g - 1) * 4;
        const float* F = feat + (size_t)b * D * N;
        float4 f = make_float4(F[(size_t)cb * N + id], F[(size_t)(cb + 1) * N + id],
                               F[(size_t)(cb + 2) * N + id], F[(size_t)(cb + 3) * N + id]);
        float* o = out + (((size_t)b * C + 3 + cb) * K + k) * S + s;
        o[0] = f.x;
        o[KS] = f.y;
        o[2 * KS] = f.z;
        o[3 * KS] = f.w;
    }
}

extern "C" void kernel_launch(void* const* d_in, const int* in_sizes, int n_in,
                              void* d_out, int out_size, void* d_ws, size_t ws_size,
                              hipStream_t stream) {
    const float* pts = (const float*)d_in[0];   // [B, 3, N]
    const float* newp = (const float*)d_in[1];  // [B, 3, S]
    const float* feat = (const float*)d_in[2];  // [B, D, N]
    float* out = (float*)d_out;                 // [B, C, K, S]

    size_t off = 0;
    int* ind = (int*)((char*)d_ws + off);        off += (size_t)B * S * K * sizeof(int);
    float4* pts4 = (float4*)((char*)d_ws + off); off += (size_t)B * N * sizeof(float4);
    float* featT = (float*)((char*)d_ws + off);
    size_t need = off + (size_t)B * N * D * sizeof(float);
    int useT = (ws_size >= need) ? 1 : 0;

    pack_kernel<<<(B * N) / 256, 256, 0, stream>>>(pts, pts4);
    if (useT) transpose_kernel<<<B * (N / 64), 256, 0, stream>>>(feat, featT);
    knn_kernel<<<(B * S) / (G * 4), 256, 0, stream>>>(pts4, newp, ind);
    if (useT)
        gather_tile_kernel<<<B * K * (S / 64), 256, 0, stream>>>(pts4, newp, featT, ind, out);
    else
        gather_kernel<<<(B * 17 * K * S) / 256, 256, 0, stream>>>(pts4, newp, feat, ind, out);
}

// Round 22
// 94.746 us; speedup vs baseline: 5.5385x; 1.3108x over previous
//
#include <hip/hip_runtime.h>

constexpr int B = 8, N = 8192, S = 2048, D = 64, K = 16, C = 3 + D;
constexpr int G = 4;  // queries per wave (R12/R17-verified structure)
constexpr int TBLKS = B * (N / 64);          // 1024 transpose blocks
constexpr int KBLKS = (B * S) / (G * 4);     // 1024 knn blocks
constexpr unsigned SMEM_BYTES = 64 * 65 * 4; // 16640 B (transpose tile; > knn's 8.3 KB)

__device__ __forceinline__ unsigned sortable(float f) {
    unsigned u = __float_as_uint(f);
    unsigned mask = (unsigned)(((int)u) >> 31) | 0x80000000u;
    return u ^ mask;
}

__device__ __forceinline__ float uload(const float* p) {
    return __uint_as_float(__builtin_amdgcn_readfirstlane(__float_as_uint(*p)));
}

// Scalar reference-exact distance (fallback path): dot asc-FMA, d=(pn-2dot)+qn [R8]
__device__ __forceinline__ float make_d(float px, float py, float pz, float pnv,
                                        float qx, float qy, float qz, float qn) {
    float dot = __fmaf_rn(pz, qz, __fmaf_rn(py, qy, __fmul_rn(px, qx)));
    return __fadd_rn(__fsub_rn(pnv, __fmul_rn(2.0f, dot)), qn);
}

// EXACT v = pn - dot2; dot2 == 2*dot bitwise (pow-2 scale commutes with rounding)
__device__ __forceinline__ float make_v(float px, float py, float pz, float pnv,
                                        float q2x, float q2y, float q2z) {
    float dot2 = __fmaf_rn(pz, q2z, __fmaf_rn(py, q2y, __fmul_rn(px, q2x)));
    return __fsub_rn(pnv, dot2);
}

__device__ __forceinline__ float bitonic_sort64_f32(float v, int lane) {
#pragma unroll
    for (int k = 2; k <= 64; k <<= 1)
#pragma unroll
        for (int j = k >> 1; j > 0; j >>= 1) {
            float o = __shfl_xor(v, j, 64);
            bool keepmin = ((lane & k) == 0) == ((lane & j) == 0);
            float mn = fminf(v, o), mx = fmaxf(v, o);
            v = keepmin ? mn : mx;
        }
    return v;
}

__device__ __forceinline__ unsigned long long bitonic_sort64_u64(unsigned long long v, int lane) {
#pragma unroll
    for (int k = 2; k <= 64; k <<= 1)
#pragma unroll
        for (int j = k >> 1; j > 0; j >>= 1) {
            unsigned long long o = __shfl_xor(v, j, 64);
            bool keepmin = ((lane & k) == 0) == ((lane & j) == 0);
            v = ((v < o) == keepmin) ? v : o;
        }
    return v;
}

// pts4[b][n] = {x, y, z, ||p||^2}; norm = (z*z + y*y) + x*x desc no-FMA [verified R8]
__global__ void pack_kernel(const float* __restrict__ pts, float4* __restrict__ pts4) {
    int t = blockIdx.x * blockDim.x + threadIdx.x;
    if (t >= B * N) return;
    int b = t >> 13, n = t & (N - 1);
    const float* P = pts + (size_t)b * 3 * N;
    float x = P[n], y = P[N + n], z = P[2 * N + n];
    float pn = __fadd_rn(__fadd_rn(__fmul_rn(z, z), __fmul_rn(y, y)), __fmul_rn(x, x));
    pts4[t] = make_float4(x, y, z, pn);
}

// Fat kernel: blocks [0,TBLKS) run the feat->featT transpose; blocks
// [TBLKS, TBLKS+KBLKS) run knn (R17-verified two-pass threshold select).
// The two halves are independent (knn reads pts4/newp only); fusing them in
// one launch overlaps the ~8us transpose under the 62us knn. Dynamic LDS is
// a union: transpose uses 64x65 f32 tile; knn uses 4x4x64 u64 buf + counters.
__global__ void __launch_bounds__(256) fused_kernel(const float* __restrict__ feat,
                                                    float* __restrict__ featT,
                                                    const float4* __restrict__ pts4,
                                                    const float* __restrict__ newp,
                                                    int* __restrict__ ind) {
    extern __shared__ char smem[];
    if (blockIdx.x < TBLKS) {
        // ===== transpose body (verified R17) =====
        float (*tile)[65] = (float(*)[65])smem;
        int b = blockIdx.x >> 7;
        int n0 = (blockIdx.x & 127) << 6;
        int col = threadIdx.x & 63;
        int crow = threadIdx.x >> 6;
        const float* F = feat + (size_t)b * D * N;
#pragma unroll
        for (int i = 0; i < 16; ++i) {
            int c = i * 4 + crow;
            tile[c][col] = F[(size_t)c * N + n0 + col];
        }
        __syncthreads();
        float* FT = featT + ((size_t)b * N + n0) * D;
#pragma unroll
        for (int i = 0; i < 16; ++i) {
            int nl = i * 4 + crow;
            FT[(size_t)nl * D + col] = tile[col][nl];
        }
        return;
    }
    // ===== knn body (verified R12/R17) =====
    unsigned long long (*buf)[G][64] = (unsigned long long(*)[G][64])smem;
    int* cnt_lds = (int*)(smem + 4 * G * 64 * sizeof(unsigned long long));  // [4][G]
    int wib = threadIdx.x >> 6;
    int lane = threadIdx.x & 63;
    int wid = (blockIdx.x - TBLKS) * 4 + wib;
    int b = wid >> 9;
    int sbase = (wid & 511) * G;
    const float4* P4 = pts4 + (size_t)b * N;
    const float* Q = newp + (size_t)b * 3 * S;
    if (lane < G) cnt_lds[wib * G + lane] = 0;
    float qx[G], qy[G], qz[G], qn[G], q2x[G], q2y[G], q2z[G];
#pragma unroll
    for (int g = 0; g < G; ++g) {
        int s = sbase + g;
        qx[g] = uload(Q + s);
        qy[g] = uload(Q + S + s);
        qz[g] = uload(Q + 2 * S + s);
        qn[g] = __fadd_rn(__fadd_rn(__fmul_rn(qz[g], qz[g]), __fmul_rn(qy[g], qy[g])),
                          __fmul_rn(qx[g], qx[g]));
        q2x[g] = 2.0f * qx[g];  // exact pow-2 scale
        q2y[g] = 2.0f * qy[g];
        q2z[g] = 2.0f * qz[g];
    }

    // ---- pass 1: per-lane min of v over 128 candidates ----
    float m[G];
#pragma unroll
    for (int g = 0; g < G; ++g) m[g] = __int_as_float(0x7f800000);
    for (int blk = 0; blk < N / 256; ++blk) {
        int nb = blk * 256 + lane;
        float4 c0 = P4[nb], c1 = P4[nb + 64], c2 = P4[nb + 128], c3 = P4[nb + 192];
#pragma unroll
        for (int g = 0; g < G; ++g) {
            float v0 = make_v(c0.x, c0.y, c0.z, c0.w, q2x[g], q2y[g], q2z[g]);
            float v1 = make_v(c1.x, c1.y, c1.z, c1.w, q2x[g], q2y[g], q2z[g]);
            float v2 = make_v(c2.x, c2.y, c2.z, c2.w, q2x[g], q2y[g], q2z[g]);
            float v3 = make_v(c3.x, c3.y, c3.z, c3.w, q2x[g], q2y[g], q2z[g]);
            m[g] = fminf(m[g], fminf(fminf(v0, v1), fminf(v2, v3)));
        }
    }
    float tau_d[G], vthr[G];
#pragma unroll
    for (int g = 0; g < G; ++g) {
        float tau_v = __shfl(bitonic_sort64_f32(m[g], lane), 15, 64);
        tau_d[g] = __fadd_rn(tau_v, qn[g]);  // valid upper bound on 16th distance
        vthr[g] = __fadd_rn(__fsub_rn(tau_d[g], qn[g]), 1e-4f);  // superset pre-filter
    }

    // ---- pass 2: pre-filter on v, exact check + LDS-atomic compact ----
    for (int blk = 0; blk < N / 256; ++blk) {
        int nb = blk * 256 + lane;
        float4 c0 = P4[nb], c1 = P4[nb + 64], c2 = P4[nb + 128], c3 = P4[nb + 192];
#pragma unroll
        for (int g = 0; g < G; ++g) {
            float vv[4];
            vv[0] = make_v(c0.x, c0.y, c0.z, c0.w, q2x[g], q2y[g], q2z[g]);
            vv[1] = make_v(c1.x, c1.y, c1.z, c1.w, q2x[g], q2y[g], q2z[g]);
            vv[2] = make_v(c2.x, c2.y, c2.z, c2.w, q2x[g], q2y[g], q2z[g]);
            vv[3] = make_v(c3.x, c3.y, c3.z, c3.w, q2x[g], q2y[g], q2z[g]);
#pragma unroll
            for (int i = 0; i < 4; ++i) {
                if (vv[i] <= vthr[g]) {  // rare divergent branch
                    float d = __fadd_rn(vv[i], qn[g]);  // exact reference d
                    if (d <= tau_d[g]) {
                        int pos = atomicAdd(&cnt_lds[wib * G + g], 1);
                        if (pos < 64)
                            buf[wib][g][pos] =
                                ((unsigned long long)sortable(d) << 32) | (unsigned)(nb + i * 64);
                    }
                }
            }
        }
    }
    __syncthreads();

#pragma unroll
    for (int g = 0; g < G; ++g) {
        int cnt = cnt_lds[wib * G + g];
        int* my_ind = ind + ((size_t)b * S + sbase + g) * K;
        if (cnt <= 64) {
            unsigned long long key = (lane < cnt) ? buf[wib][g][lane] : ~0ull;
            key = bitonic_sort64_u64(key, lane);
            if (lane < K) my_ind[lane] = (int)(unsigned)key;
        } else {
            // Exact fallback (never expected on random data)
            unsigned long long a[K];
#pragma unroll
            for (int i = 0; i < K; ++i) a[i] = ~0ull;
            for (int n = lane; n < N; n += 64) {
                float4 c = P4[n];
                float d = make_d(c.x, c.y, c.z, c.w, qx[g], qy[g], qz[g], qn[g]);
                unsigned long long key = ((unsigned long long)sortable(d) << 32) | (unsigned)n;
                if (key < a[K - 1]) {
#pragma unroll
                    for (int i = K - 1; i >= 1; --i) {
                        unsigned long long lo = a[i - 1];
                        a[i] = key < lo ? lo : (key < a[i] ? key : a[i]);
                    }
                    a[0] = key < a[0] ? key : a[0];
                }
            }
            for (int r = 0; r < K; ++r) {
                unsigned long long best = a[0];
#pragma unroll
                for (int mm = 1; mm < 64; mm <<= 1) {
                    unsigned long long o = __shfl_xor(best, mm, 64);
                    best = o < best ? o : best;
                }
                if (lane == 0) my_ind[r] = (int)(unsigned)best;
                bool won = (a[0] == best);
#pragma unroll
                for (int i = 0; i < K - 1; ++i) a[i] = won ? a[i + 1] : a[i];
                a[K - 1] = won ? ~0ull : a[K - 1];
            }
        }
    }
}

// Standalone knn (fallback path when no featT workspace -> no transpose to fuse)
__global__ void __launch_bounds__(256) knn_kernel(const float4* __restrict__ pts4,
                                                  const float* __restrict__ newp,
                                                  int* __restrict__ ind) {
    __shared__ unsigned long long buf[4][G][64];
    __shared__ int cnt_lds[4][G];
    int wib = threadIdx.x >> 6;
    int lane = threadIdx.x & 63;
    int wid = blockIdx.x * 4 + wib;
    int b = wid >> 9;
    int sbase = (wid & 511) * G;
    const float4* P4 = pts4 + (size_t)b * N;
    const float* Q = newp + (size_t)b * 3 * S;
    if (lane < G) cnt_lds[wib][lane] = 0;
    float qx[G], qy[G], qz[G], qn[G], q2x[G], q2y[G], q2z[G];
#pragma unroll
    for (int g = 0; g < G; ++g) {
        int s = sbase + g;
        qx[g] = uload(Q + s);
        qy[g] = uload(Q + S + s);
        qz[g] = uload(Q + 2 * S + s);
        qn[g] = __fadd_rn(__fadd_rn(__fmul_rn(qz[g], qz[g]), __fmul_rn(qy[g], qy[g])),
                          __fmul_rn(qx[g], qx[g]));
        q2x[g] = 2.0f * qx[g];
        q2y[g] = 2.0f * qy[g];
        q2z[g] = 2.0f * qz[g];
    }
    float m[G];
#pragma unroll
    for (int g = 0; g < G; ++g) m[g] = __int_as_float(0x7f800000);
    for (int blk = 0; blk < N / 256; ++blk) {
        int nb = blk * 256 + lane;
        float4 c0 = P4[nb], c1 = P4[nb + 64], c2 = P4[nb + 128], c3 = P4[nb + 192];
#pragma unroll
        for (int g = 0; g < G; ++g) {
            float v0 = make_v(c0.x, c0.y, c0.z, c0.w, q2x[g], q2y[g], q2z[g]);
            float v1 = make_v(c1.x, c1.y, c1.z, c1.w, q2x[g], q2y[g], q2z[g]);
            float v2 = make_v(c2.x, c2.y, c2.z, c2.w, q2x[g], q2y[g], q2z[g]);
            float v3 = make_v(c3.x, c3.y, c3.z, c3.w, q2x[g], q2y[g], q2z[g]);
            m[g] = fminf(m[g], fminf(fminf(v0, v1), fminf(v2, v3)));
        }
    }
    float tau_d[G], vthr[G];
#pragma unroll
    for (int g = 0; g < G; ++g) {
        float tau_v = __shfl(bitonic_sort64_f32(m[g], lane), 15, 64);
        tau_d[g] = __fadd_rn(tau_v, qn[g]);
        vthr[g] = __fadd_rn(__fsub_rn(tau_d[g], qn[g]), 1e-4f);
    }
    for (int blk = 0; blk < N / 256; ++blk) {
        int nb = blk * 256 + lane;
        float4 c0 = P4[nb], c1 = P4[nb + 64], c2 = P4[nb + 128], c3 = P4[nb + 192];
#pragma unroll
        for (int g = 0; g < G; ++g) {
            float vv[4];
            vv[0] = make_v(c0.x, c0.y, c0.z, c0.w, q2x[g], q2y[g], q2z[g]);
            vv[1] = make_v(c1.x, c1.y, c1.z, c1.w, q2x[g], q2y[g], q2z[g]);
            vv[2] = make_v(c2.x, c2.y, c2.z, c2.w, q2x[g], q2y[g], q2z[g]);
            vv[3] = make_v(c3.x, c3.y, c3.z, c3.w, q2x[g], q2y[g], q2z[g]);
#pragma unroll
            for (int i = 0; i < 4; ++i) {
                if (vv[i] <= vthr[g]) {
                    float d = __fadd_rn(vv[i], qn[g]);
                    if (d <= tau_d[g]) {
                        int pos = atomicAdd(&cnt_lds[wib][g], 1);
                        if (pos < 64)
                            buf[wib][g][pos] =
                                ((unsigned long long)sortable(d) << 32) | (unsigned)(nb + i * 64);
                    }
                }
            }
        }
    }
    __syncthreads();
#pragma unroll
    for (int g = 0; g < G; ++g) {
        int cnt = cnt_lds[wib][g];
        int* my_ind = ind + ((size_t)b * S + sbase + g) * K;
        if (cnt <= 64) {
            unsigned long long key = (lane < cnt) ? buf[wib][g][lane] : ~0ull;
            key = bitonic_sort64_u64(key, lane);
            if (lane < K) my_ind[lane] = (int)(unsigned)key;
        } else {
            unsigned long long a[K];
#pragma unroll
            for (int i = 0; i < K; ++i) a[i] = ~0ull;
            for (int n = lane; n < N; n += 64) {
                float4 c = P4[n];
                float d = make_d(c.x, c.y, c.z, c.w, qx[g], qy[g], qz[g], qn[g]);
                unsigned long long key = ((unsigned long long)sortable(d) << 32) | (unsigned)n;
                if (key < a[K - 1]) {
#pragma unroll
                    for (int i = K - 1; i >= 1; --i) {
                        unsigned long long lo = a[i - 1];
                        a[i] = key < lo ? lo : (key < a[i] ? key : a[i]);
                    }
                    a[0] = key < a[0] ? key : a[0];
                }
            }
            for (int r = 0; r < K; ++r) {
                unsigned long long best = a[0];
#pragma unroll
                for (int mm = 1; mm < 64; mm <<= 1) {
                    unsigned long long o = __shfl_xor(best, mm, 64);
                    best = o < best ? o : best;
                }
                if (lane == 0) my_ind[r] = (int)(unsigned)best;
                bool won = (a[0] == best);
#pragma unroll
                for (int i = 0; i < K - 1; ++i) a[i] = won ? a[i + 1] : a[i];
                a[K - 1] = won ? ~0ull : a[K - 1];
            }
        }
    }
}

// ===== gather: LDS-staged tile (verified R17) =====
__global__ void __launch_bounds__(256) gather_tile_kernel(const float4* __restrict__ pts4,
                                                          const float* __restrict__ newp,
                                                          const float* __restrict__ featT,
                                                          const int* __restrict__ ind,
                                                          float* __restrict__ out) {
    __shared__ float tile[64][69];
    int bid = blockIdx.x;
    int b = bid >> 9;
    int k = (bid >> 5) & (K - 1);
    int s0 = (bid & 31) << 6;
    int j = threadIdx.x >> 2;
    int p = threadIdx.x & 3;
    int s = s0 + j;
    int id = ind[((size_t)b * S + s) * K + k];
    const float* row = featT + ((size_t)b * N + id) * D;
#pragma unroll
    for (int i = 0; i < 4; ++i) {
        int f = p + 4 * i;
        float4 v = *(const float4*)(row + f * 4);
        *(float4*)(&tile[j][3 + f * 4]) = v;
    }
    if (p == 0) {
        float4 pt = pts4[(size_t)b * N + id];
        const float* Q = newp + (size_t)b * 3 * S;
        tile[j][0] = __fsub_rn(pt.x, Q[s]);
        tile[j][1] = __fsub_rn(pt.y, Q[S + s]);
        tile[j][2] = __fsub_rn(pt.z, Q[2 * S + s]);
    }
    __syncthreads();
    size_t KS = (size_t)K * S;
    float* ob = out + ((size_t)b * C * K + k) * S + s0;
#pragma unroll
    for (int it = 0; it < 17; ++it) {
        int c = it * 4 + (threadIdx.x >> 6);
        int l = threadIdx.x & 63;
        if (c < C) ob[(size_t)c * KS + l] = tile[l][c];
    }
}

// Fallback gather (no featT workspace)
__global__ void __launch_bounds__(256) gather_kernel(const float4* __restrict__ pts4,
                                                     const float* __restrict__ newp,
                                                     const float* __restrict__ feat,
                                                     const int* __restrict__ ind,
                                                     float* __restrict__ out) {
    int t = blockIdx.x * blockDim.x + threadIdx.x;
    int s = t & (S - 1);
    int k = (t >> 11) & (K - 1);
    int rest = t >> 15;
    int g = rest % 17;
    int b = rest / 17;
    if (b >= B) return;
    int id = ind[((size_t)b * S + s) * K + k];
    size_t KS = (size_t)K * S;
    if (g == 0) {
        float4 p = pts4[(size_t)b * N + id];
        const float* Q = newp + (size_t)b * 3 * S;
        float* o = out + ((size_t)b * C * K + k) * S + s;
        o[0] = __fsub_rn(p.x, Q[s]);
        o[KS] = __fsub_rn(p.y, Q[S + s]);
        o[2 * KS] = __fsub_rn(p.z, Q[2 * S + s]);
    } else {
        int cb = (g - 1) * 4;
        const float* F = feat + (size_t)b * D * N;
        float4 f = make_float4(F[(size_t)cb * N + id], F[(size_t)(cb + 1) * N + id],
                               F[(size_t)(cb + 2) * N + id], F[(size_t)(cb + 3) * N + id]);
        float* o = out + (((size_t)b * C + 3 + cb) * K + k) * S + s;
        o[0] = f.x;
        o[KS] = f.y;
        o[2 * KS] = f.z;
        o[3 * KS] = f.w;
    }
}

extern "C" void kernel_launch(void* const* d_in, const int* in_sizes, int n_in,
                              void* d_out, int out_size, void* d_ws, size_t ws_size,
                              hipStream_t stream) {
    const float* pts = (const float*)d_in[0];   // [B, 3, N]
    const float* newp = (const float*)d_in[1];  // [B, 3, S]
    const float* feat = (const float*)d_in[2];  // [B, D, N]
    float* out = (float*)d_out;                 // [B, C, K, S]

    size_t off = 0;
    int* ind = (int*)((char*)d_ws + off);        off += (size_t)B * S * K * sizeof(int);
    float4* pts4 = (float4*)((char*)d_ws + off); off += (size_t)B * N * sizeof(float4);
    float* featT = (float*)((char*)d_ws + off);
    size_t need = off + (size_t)B * N * D * sizeof(float);
    int useT = (ws_size >= need) ? 1 : 0;

    pack_kernel<<<(B * N) / 256, 256, 0, stream>>>(pts, pts4);
    if (useT) {
        fused_kernel<<<TBLKS + KBLKS, 256, SMEM_BYTES, stream>>>(feat, featT, pts4, newp, ind);
        gather_tile_kernel<<<B * K * (S / 64), 256, 0, stream>>>(pts4, newp, featT, ind, out);
    } else {
        knn_kernel<<<KBLKS, 256, 0, stream>>>(pts4, newp, ind);
        gather_kernel<<<(B * 17 * K * S) / 256, 256, 0, stream>>>(pts4, newp, feat, ind, out);
    }
}

// Round 23
// 91.461 us; speedup vs baseline: 5.7374x; 1.0359x over previous
//
#include <hip/hip_runtime.h>

constexpr int B = 8, N = 8192, S = 2048, D = 64, K = 16, C = 3 + D;
constexpr int G = 4;  // queries per wave (R12-verified structure)

// Map float -> monotonically sortable unsigned (total order matches float <)
__device__ __forceinline__ unsigned sortable(float f) {
    unsigned u = __float_as_uint(f);
    unsigned mask = (unsigned)(((int)u) >> 31) | 0x80000000u;
    return u ^ mask;
}

// Wave-uniform load -> SGPR
__device__ __forceinline__ float uload(const float* p) {
    return __uint_as_float(__builtin_amdgcn_readfirstlane(__float_as_uint(*p)));
}

// Scalar reference-exact distance (fallback path): dot asc-FMA, d=(pn-2dot)+qn [R8]
__device__ __forceinline__ float make_d(float px, float py, float pz, float pnv,
                                        float qx, float qy, float qz, float qn) {
    float dot = __fmaf_rn(pz, qz, __fmaf_rn(py, qy, __fmul_rn(px, qx)));
    return __fadd_rn(__fsub_rn(pnv, __fmul_rn(2.0f, dot)), qn);
}

// EXACT v = pn - dot2; dot2 = fma(pz,q2z, fma(py,q2y, px*q2x)) == 2*dot bitwise
__device__ __forceinline__ float make_v(float px, float py, float pz, float pnv,
                                        float q2x, float q2y, float q2z) {
    float dot2 = __fmaf_rn(pz, q2z, __fmaf_rn(py, q2y, __fmul_rn(px, q2x)));
    return __fsub_rn(pnv, dot2);
}

__device__ __forceinline__ float bitonic_sort64_f32(float v, int lane) {
#pragma unroll
    for (int k = 2; k <= 64; k <<= 1)
#pragma unroll
        for (int j = k >> 1; j > 0; j >>= 1) {
            float o = __shfl_xor(v, j, 64);
            bool keepmin = ((lane & k) == 0) == ((lane & j) == 0);
            float mn = fminf(v, o), mx = fmaxf(v, o);
            v = keepmin ? mn : mx;
        }
    return v;
}

__device__ __forceinline__ unsigned long long bitonic_sort64_u64(unsigned long long v, int lane) {
#pragma unroll
    for (int k = 2; k <= 64; k <<= 1)
#pragma unroll
        for (int j = k >> 1; j > 0; j >>= 1) {
            unsigned long long o = __shfl_xor(v, j, 64);
            bool keepmin = ((lane & k) == 0) == ((lane & j) == 0);
            v = ((v < o) == keepmin) ? v : o;
        }
    return v;
}

// pts4[b][n] = {x, y, z, ||p||^2}; norm = (z*z + y*y) + x*x desc no-FMA [verified R8]
__global__ void pack_kernel(const float* __restrict__ pts, float4* __restrict__ pts4) {
    int t = blockIdx.x * blockDim.x + threadIdx.x;
    if (t >= B * N) return;
    int b = t >> 13, n = t & (N - 1);
    const float* P = pts + (size_t)b * 3 * N;
    float x = P[n], y = P[N + n], z = P[2 * N + n];
    float pn = __fadd_rn(__fadd_rn(__fmul_rn(z, z), __fmul_rn(y, y)), __fmul_rn(x, x));
    pts4[t] = make_float4(x, y, z, pn);
}

// feat [B][D][N] -> featT [B][N][D], LDS-tiled 64x64
__global__ void __launch_bounds__(256) transpose_kernel(const float* __restrict__ feat,
                                                        float* __restrict__ featT) {
    __shared__ float tile[64][65];
    int b = blockIdx.x >> 7;
    int n0 = (blockIdx.x & 127) << 6;
    int col = threadIdx.x & 63;
    int crow = threadIdx.x >> 6;
    const float* F = feat + (size_t)b * D * N;
#pragma unroll
    for (int i = 0; i < 16; ++i) {
        int c = i * 4 + crow;
        tile[c][col] = F[(size_t)c * N + n0 + col];
    }
    __syncthreads();
    float* FT = featT + ((size_t)b * N + n0) * D;
#pragma unroll
    for (int i = 0; i < 16; ++i) {
        int nl = i * 4 + crow;
        FT[(size_t)nl * D + col] = tile[col][nl];
    }
}

// ===== knn: R12 structure (62 us floor, converged) =====
__global__ void __launch_bounds__(256) knn_kernel(const float4* __restrict__ pts4,
                                                  const float* __restrict__ newp,
                                                  int* __restrict__ ind) {
    __shared__ unsigned long long buf[4][G][64];
    __shared__ int cnt_lds[4][G];
    int wib = threadIdx.x >> 6;
    int lane = threadIdx.x & 63;
    int wid = blockIdx.x * 4 + wib;
    int b = wid >> 9;
    int sbase = (wid & 511) * G;
    const float4* P4 = pts4 + (size_t)b * N;
    const float* Q = newp + (size_t)b * 3 * S;
    if (lane < G) cnt_lds[wib][lane] = 0;
    float qx[G], qy[G], qz[G], qn[G], q2x[G], q2y[G], q2z[G];
#pragma unroll
    for (int g = 0; g < G; ++g) {
        int s = sbase + g;
        qx[g] = uload(Q + s);
        qy[g] = uload(Q + S + s);
        qz[g] = uload(Q + 2 * S + s);
        qn[g] = __fadd_rn(__fadd_rn(__fmul_rn(qz[g], qz[g]), __fmul_rn(qy[g], qy[g])),
                          __fmul_rn(qx[g], qx[g]));
        q2x[g] = 2.0f * qx[g];  // exact pow-2 scale
        q2y[g] = 2.0f * qy[g];
        q2z[g] = 2.0f * qz[g];
    }

    // ---- pass 1: per-lane min of v over 128 candidates ----
    float m[G];
#pragma unroll
    for (int g = 0; g < G; ++g) m[g] = __int_as_float(0x7f800000);
    for (int blk = 0; blk < N / 256; ++blk) {
        int nb = blk * 256 + lane;
        float4 c0 = P4[nb], c1 = P4[nb + 64], c2 = P4[nb + 128], c3 = P4[nb + 192];
#pragma unroll
        for (int g = 0; g < G; ++g) {
            float v0 = make_v(c0.x, c0.y, c0.z, c0.w, q2x[g], q2y[g], q2z[g]);
            float v1 = make_v(c1.x, c1.y, c1.z, c1.w, q2x[g], q2y[g], q2z[g]);
            float v2 = make_v(c2.x, c2.y, c2.z, c2.w, q2x[g], q2y[g], q2z[g]);
            float v3 = make_v(c3.x, c3.y, c3.z, c3.w, q2x[g], q2y[g], q2z[g]);
            m[g] = fminf(m[g], fminf(fminf(v0, v1), fminf(v2, v3)));
        }
    }
    float tau_d[G], vthr[G];
#pragma unroll
    for (int g = 0; g < G; ++g) {
        float tau_v = __shfl(bitonic_sort64_f32(m[g], lane), 15, 64);
        tau_d[g] = __fadd_rn(tau_v, qn[g]);  // valid upper bound on 16th distance
        vthr[g] = __fadd_rn(__fsub_rn(tau_d[g], qn[g]), 1e-4f);  // superset pre-filter
    }

    // ---- pass 2: pre-filter on v, exact check + LDS-atomic compact ----
    for (int blk = 0; blk < N / 256; ++blk) {
        int nb = blk * 256 + lane;
        float4 c0 = P4[nb], c1 = P4[nb + 64], c2 = P4[nb + 128], c3 = P4[nb + 192];
#pragma unroll
        for (int g = 0; g < G; ++g) {
            float vv[4];
            vv[0] = make_v(c0.x, c0.y, c0.z, c0.w, q2x[g], q2y[g], q2z[g]);
            vv[1] = make_v(c1.x, c1.y, c1.z, c1.w, q2x[g], q2y[g], q2z[g]);
            vv[2] = make_v(c2.x, c2.y, c2.z, c2.w, q2x[g], q2y[g], q2z[g]);
            vv[3] = make_v(c3.x, c3.y, c3.z, c3.w, q2x[g], q2y[g], q2z[g]);
#pragma unroll
            for (int i = 0; i < 4; ++i) {
                if (vv[i] <= vthr[g]) {  // rare divergent branch
                    float d = __fadd_rn(vv[i], qn[g]);  // exact reference d
                    if (d <= tau_d[g]) {
                        int pos = atomicAdd(&cnt_lds[wib][g], 1);
                        if (pos < 64)
                            buf[wib][g][pos] =
                                ((unsigned long long)sortable(d) << 32) | (unsigned)(nb + i * 64);
                    }
                }
            }
        }
    }
    __syncthreads();

#pragma unroll
    for (int g = 0; g < G; ++g) {
        int cnt = cnt_lds[wib][g];
        int* my_ind = ind + ((size_t)b * S + sbase + g) * K;
        if (cnt <= 64) {
            unsigned long long key = (lane < cnt) ? buf[wib][g][lane] : ~0ull;
            key = bitonic_sort64_u64(key, lane);
            if (lane < K) my_ind[lane] = (int)(unsigned)key;
        } else {
            // Exact fallback (never expected on random data)
            unsigned long long a[K];
#pragma unroll
            for (int i = 0; i < K; ++i) a[i] = ~0ull;
            for (int n = lane; n < N; n += 64) {
                float4 c = P4[n];
                float d = make_d(c.x, c.y, c.z, c.w, qx[g], qy[g], qz[g], qn[g]);
                unsigned long long key = ((unsigned long long)sortable(d) << 32) | (unsigned)n;
                if (key < a[K - 1]) {
#pragma unroll
                    for (int i = K - 1; i >= 1; --i) {
                        unsigned long long lo = a[i - 1];
                        a[i] = key < lo ? lo : (key < a[i] ? key : a[i]);
                    }
                    a[0] = key < a[0] ? key : a[0];
                }
            }
            for (int r = 0; r < K; ++r) {
                unsigned long long best = a[0];
#pragma unroll
                for (int mm = 1; mm < 64; mm <<= 1) {
                    unsigned long long o = __shfl_xor(best, mm, 64);
                    best = o < best ? o : best;
                }
                if (lane == 0) my_ind[r] = (int)(unsigned)best;
                bool won = (a[0] == best);
#pragma unroll
                for (int i = 0; i < K - 1; ++i) a[i] = won ? a[i + 1] : a[i];
                a[K - 1] = won ? ~0ull : a[K - 1];
            }
        }
    }
}

// ===== gather: LDS-staged tile. Block = (b, k, 64-s tile). =====
// Phase 1: 4 lanes per neighbor read the full 256B featT row (4-lane-contiguous
// 64B segments -> 16 line-transactions per wave-load) + coords; stage in LDS
// tile[64 s][69 pad]. Phase 2: coalesced 256B stores per (c, s-run).
__global__ void __launch_bounds__(256) gather_tile_kernel(const float4* __restrict__ pts4,
                                                          const float* __restrict__ newp,
                                                          const float* __restrict__ featT,
                                                          const int* __restrict__ ind,
                                                          float* __restrict__ out) {
    __shared__ float tile[64][69];  // odd stride: phase-2 reads <=2-way bank alias
    int bid = blockIdx.x;           // b*(K*32) + k*32 + st
    int b = bid >> 9;               // K*32 = 512
    int k = (bid >> 5) & (K - 1);
    int s0 = (bid & 31) << 6;
    int j = threadIdx.x >> 2;  // neighbor (s-lane) 0..63
    int p = threadIdx.x & 3;   // row piece 0..3
    int s = s0 + j;
    int id = ind[((size_t)b * S + s) * K + k];
    const float* row = featT + ((size_t)b * N + id) * D;
    // feature channels: piece p covers float4 indices {p, p+4, p+8, p+12}
#pragma unroll
    for (int i = 0; i < 4; ++i) {
        int f = p + 4 * i;
        float4 v = *(const float4*)(row + f * 4);
        *(float4*)(&tile[j][3 + f * 4]) = v;
    }
    // coords (p==0 lanes only): tile[j][0..2] = pts4[id].xyz - newp[b][*][s]
    if (p == 0) {
        float4 pt = pts4[(size_t)b * N + id];
        const float* Q = newp + (size_t)b * 3 * S;
        tile[j][0] = __fsub_rn(pt.x, Q[s]);
        tile[j][1] = __fsub_rn(pt.y, Q[S + s]);
        tile[j][2] = __fsub_rn(pt.z, Q[2 * S + s]);
    }
    __syncthreads();
    // phase 2: 4 channels x 64 s per iteration, 17 iterations (68 slots, 67 used)
    size_t KS = (size_t)K * S;
    float* ob = out + ((size_t)b * C * K + k) * S + s0;
#pragma unroll
    for (int it = 0; it < 17; ++it) {
        int c = it * 4 + (threadIdx.x >> 6);
        int l = threadIdx.x & 63;
        if (c < C) ob[(size_t)c * KS + l] = tile[l][c];
    }
}

// Fallback gather (no featT workspace): per-thread reads from channel-major feat.
__global__ void __launch_bounds__(256) gather_kernel(const float4* __restrict__ pts4,
                                                     const float* __restrict__ newp,
                                                     const float* __restrict__ feat,
                                                     const int* __restrict__ ind,
                                                     float* __restrict__ out) {
    int t = blockIdx.x * blockDim.x + threadIdx.x;
    int s = t & (S - 1);
    int k = (t >> 11) & (K - 1);
    int rest = t >> 15;
    int g = rest % 17;
    int b = rest / 17;
    if (b >= B) return;
    int id = ind[((size_t)b * S + s) * K + k];
    size_t KS = (size_t)K * S;
    if (g == 0) {
        float4 p = pts4[(size_t)b * N + id];
        const float* Q = newp + (size_t)b * 3 * S;
        float* o = out + ((size_t)b * C * K + k) * S + s;
        o[0] = __fsub_rn(p.x, Q[s]);
        o[KS] = __fsub_rn(p.y, Q[S + s]);
        o[2 * KS] = __fsub_rn(p.z, Q[2 * S + s]);
    } else {
        int cb = (g - 1) * 4;
        const float* F = feat + (size_t)b * D * N;
        float4 f = make_float4(F[(size_t)cb * N + id], F[(size_t)(cb + 1) * N + id],
                               F[(size_t)(cb + 2) * N + id], F[(size_t)(cb + 3) * N + id]);
        float* o = out + (((size_t)b * C + 3 + cb) * K + k) * S + s;
        o[0] = f.x;
        o[KS] = f.y;
        o[2 * KS] = f.z;
        o[3 * KS] = f.w;
    }
}

extern "C" void kernel_launch(void* const* d_in, const int* in_sizes, int n_in,
                              void* d_out, int out_size, void* d_ws, size_t ws_size,
                              hipStream_t stream) {
    const float* pts = (const float*)d_in[0];   // [B, 3, N]
    const float* newp = (const float*)d_in[1];  // [B, 3, S]
    const float* feat = (const float*)d_in[2];  // [B, D, N]
    float* out = (float*)d_out;                 // [B, C, K, S]

    size_t off_ind = 0;
    size_t off_pts4 = (size_t)B * S * K * sizeof(int);              // 2 MB
    size_t off_featT = off_pts4 + (size_t)B * N * sizeof(float4);   // +1 MB
    size_t need = off_featT + (size_t)B * N * D * sizeof(float);    // +16 MB
    int* ind = (int*)((char*)d_ws + off_ind);
    float4* pts4 = (float4*)((char*)d_ws + off_pts4);
    float* featT = (float*)((char*)d_ws + off_featT);
    int useT = (ws_size >= need) ? 1 : 0;

    pack_kernel<<<(B * N) / 256, 256, 0, stream>>>(pts, pts4);
    if (useT) transpose_kernel<<<B * (N / 64), 256, 0, stream>>>(feat, featT);
    knn_kernel<<<(B * S) / (G * 4), 256, 0, stream>>>(pts4, newp, ind);
    if (useT)
        gather_tile_kernel<<<B * K * (S / 64), 256, 0, stream>>>(pts4, newp, featT, ind, out);
    else
        gather_kernel<<<(B * 17 * K * S) / 256, 256, 0, stream>>>(pts4, newp, feat, ind, out);
}